// Round 1
// baseline (911.291 us; speedup 1.0000x reference)
//
#include <hip/hip_runtime.h>

// Problem constants (B=4, L=2048, C=512, H=8, D=64)
#define CDIM 512
#define LDIM 2048
#define BDIM 4
#define HDIM 8
#define DDIM 64
#define QKV_STRIDE (BDIM*HDIM*LDIM*DDIM)   // 4194304 floats per q/k/v buffer

// ---------------------------------------------------------------------------
// Kernel 1: qkv = x @ qkv_w^T + b, scattered into q/k/v buffers (B,H,L,D) fp32.
// A = x (8192 x 512 row-major), B = qkv_w (1536 x 512 row-major), shared K dim.
// 128x128 tile, BK=16, 256 threads, 8x8 accumulators per thread.
// ---------------------------------------------------------------------------
__global__ __launch_bounds__(256) void qkv_gemm_kernel(
    const float* __restrict__ x, const float* __restrict__ w,
    const float* __restrict__ bias, float* __restrict__ qkv) {
  __shared__ float As[16][132];   // k-major: As[k][m], pad 132 breaks conflicts
  __shared__ float Bs[16][132];
  const int t  = threadIdx.x;
  const int tx = t & 15, ty = t >> 4;
  const int m0 = blockIdx.y * 128, n0 = blockIdx.x * 128;

  float acc[8][8];
  #pragma unroll
  for (int i = 0; i < 8; ++i)
    #pragma unroll
    for (int j = 0; j < 8; ++j) acc[i][j] = 0.f;

  for (int kt = 0; kt < CDIM; kt += 16) {
    #pragma unroll
    for (int s = 0; s < 2; ++s) {
      const int slot = t + s * 256;          // 512 float4 slots (128 rows x 4)
      const int row = slot >> 2, c4 = (slot & 3) * 4;
      const float4 av = *(const float4*)(x + (size_t)(m0 + row) * CDIM + kt + c4);
      As[c4+0][row] = av.x; As[c4+1][row] = av.y; As[c4+2][row] = av.z; As[c4+3][row] = av.w;
      const float4 bv = *(const float4*)(w + (size_t)(n0 + row) * CDIM + kt + c4);
      Bs[c4+0][row] = bv.x; Bs[c4+1][row] = bv.y; Bs[c4+2][row] = bv.z; Bs[c4+3][row] = bv.w;
    }
    __syncthreads();
    #pragma unroll
    for (int kk = 0; kk < 16; ++kk) {
      float a[8], b[8];
      *(float4*)&a[0] = *(const float4*)&As[kk][ty * 8];
      *(float4*)&a[4] = *(const float4*)&As[kk][ty * 8 + 4];
      *(float4*)&b[0] = *(const float4*)&Bs[kk][tx * 8];
      *(float4*)&b[4] = *(const float4*)&Bs[kk][tx * 8 + 4];
      #pragma unroll
      for (int i = 0; i < 8; ++i)
        #pragma unroll
        for (int j = 0; j < 8; ++j) acc[i][j] += a[i] * b[j];
    }
    __syncthreads();
  }

  // Epilogue: scatter to q/k/v (B,H,L,D). Thread cols n..n+7 stay in one head.
  const int n   = n0 + tx * 8;
  const int typ = n >> 9;             // 0=q 1=k 2=v
  const int hh  = (n >> 6) & 7;
  const int d0  = n & 63;
  float bv[8];
  #pragma unroll
  for (int j = 0; j < 8; ++j) bv[j] = bias[n + j];
  #pragma unroll
  for (int i = 0; i < 8; ++i) {
    const int m  = m0 + ty * 8 + i;
    const int bb = m >> 11;           // / 2048
    const int l  = m & 2047;
    float* dst = qkv + (size_t)typ * QKV_STRIDE
               + (((size_t)((bb * HDIM + hh) * LDIM + l)) << 6) + d0;
    *(float4*)(dst)     = make_float4(acc[i][0]+bv[0], acc[i][1]+bv[1],
                                      acc[i][2]+bv[2], acc[i][3]+bv[3]);
    *(float4*)(dst + 4) = make_float4(acc[i][4]+bv[4], acc[i][5]+bv[5],
                                      acc[i][6]+bv[6], acc[i][7]+bv[7]);
  }
}

// ---------------------------------------------------------------------------
// Kernel 2: in-place RoPE on q and k buffers. Q rows [0,65536), K rows
// [65536,131072) are contiguous. One thread rotates one (d, d+32) pair.
// rope(x)[d]    = x[d]*cos[l,d]    - x[d+32]*sin[l,d]      (d < 32)
// rope(x)[d+32] = x[d+32]*cos[l,d+32] + x[d]*sin[l,d+32]
// ---------------------------------------------------------------------------
__global__ __launch_bounds__(256) void rope_kernel(
    float* __restrict__ qkv, const float* __restrict__ cosT,
    const float* __restrict__ sinT) {
  const int t   = threadIdx.x;
  const int rid = blockIdx.x * 8 + (t >> 5);   // row id over q then k
  const int d   = t & 31;
  const int l   = rid & 2047;
  float* p = qkv + ((size_t)rid << 6);
  const float x1 = p[d], x2 = p[d + 32];
  const float c1 = cosT[l * 64 + d],      s1 = sinT[l * 64 + d];
  const float c2 = cosT[l * 64 + d + 32], s2 = sinT[l * 64 + d + 32];
  p[d]      = x1 * c1 - x2 * s1;
  p[d + 32] = x2 * c2 + x1 * s2;
}

// ---------------------------------------------------------------------------
// Kernel 3: flash attention, fp32. Block = 64 q-rows of one (b,h); iterates
// 32 KV tiles of 64. 256 threads (16x16), each owns 4x4 of S/O.
// LDS: Qt/Kt (d-major), V (kv-major), Pt (kv-major) -- 4 x 16KB = 64KB.
// All inner-loop reads are broadcast or conflict-free b128.
// Output overwrites the q region (block consumed its Q tile already).
// ---------------------------------------------------------------------------
__global__ __launch_bounds__(256) void attn_kernel(float* __restrict__ qkv) {
  __shared__ float Qts[64][64];   // [d][qrow]
  __shared__ float Kts[64][64];   // [d][kvrow]
  __shared__ float Vs [64][64];   // [kvrow][d]
  __shared__ float Pst[64][64];   // [kvrow][qrow]
  const int t  = threadIdx.x;
  const int tx = t & 15, ty = t >> 4;
  const int bh = blockIdx.y;
  const int q0 = blockIdx.x * 64;
  float* Qp       = qkv + (size_t)bh * (LDIM * DDIM);
  const float* Kp = Qp + QKV_STRIDE;
  const float* Vp = Kp + QKV_STRIDE;

  // stage Q tile (transposed)
  #pragma unroll
  for (int s = 0; s < 4; ++s) {
    const int slot = t + s * 256;            // 1024 slots = 64 rows x 16 float4
    const int r = slot >> 4, c4 = (slot & 15) * 4;
    const float4 v = *(const float4*)(Qp + (size_t)(q0 + r) * 64 + c4);
    Qts[c4+0][r] = v.x; Qts[c4+1][r] = v.y; Qts[c4+2][r] = v.z; Qts[c4+3][r] = v.w;
  }

  float o[4][4];
  float mrun[4], lrun[4];
  #pragma unroll
  for (int i = 0; i < 4; ++i) {
    mrun[i] = -1e30f; lrun[i] = 0.f;
    #pragma unroll
    for (int j = 0; j < 4; ++j) o[i][j] = 0.f;
  }

  for (int kt = 0; kt < 32; ++kt) {
    __syncthreads();   // previous PV done (and Q staged, first iter)
    #pragma unroll
    for (int s = 0; s < 4; ++s) {
      const int slot = t + s * 256;
      const int r = slot >> 4, c4 = (slot & 15) * 4;
      const float4 kv = *(const float4*)(Kp + (size_t)(kt * 64 + r) * 64 + c4);
      Kts[c4+0][r] = kv.x; Kts[c4+1][r] = kv.y; Kts[c4+2][r] = kv.z; Kts[c4+3][r] = kv.w;
      const float4 vv = *(const float4*)(Vp + (size_t)(kt * 64 + r) * 64 + c4);
      Vs[r][c4+0] = vv.x; Vs[r][c4+1] = vv.y; Vs[r][c4+2] = vv.z; Vs[r][c4+3] = vv.w;
    }
    __syncthreads();

    // S = scale * Q K^T   (4x4 per thread)
    float sv[4][4];
    #pragma unroll
    for (int i = 0; i < 4; ++i)
      #pragma unroll
      for (int j = 0; j < 4; ++j) sv[i][j] = 0.f;
    #pragma unroll 16
    for (int d = 0; d < 64; ++d) {
      const float4 qa = *(const float4*)&Qts[d][ty * 4];
      const float4 kb = *(const float4*)&Kts[d][tx * 4];
      const float a[4] = {qa.x, qa.y, qa.z, qa.w};
      const float b[4] = {kb.x, kb.y, kb.z, kb.w};
      #pragma unroll
      for (int i = 0; i < 4; ++i)
        #pragma unroll
        for (int j = 0; j < 4; ++j) sv[i][j] += a[i] * b[j];
    }

    // online softmax (rows owned by the 16 lanes sharing ty)
    #pragma unroll
    for (int i = 0; i < 4; ++i) {
      float mx = -1e30f;
      #pragma unroll
      for (int j = 0; j < 4; ++j) { sv[i][j] *= 0.125f; mx = fmaxf(mx, sv[i][j]); }
      #pragma unroll
      for (int mk = 1; mk < 16; mk <<= 1) mx = fmaxf(mx, __shfl_xor(mx, mk, 16));
      const float newm  = fmaxf(mrun[i], mx);
      const float alpha = __expf(mrun[i] - newm);
      mrun[i] = newm;
      float rs = 0.f;
      float p[4];
      #pragma unroll
      for (int j = 0; j < 4; ++j) { p[j] = __expf(sv[i][j] - newm); rs += p[j]; }
      #pragma unroll
      for (int mk = 1; mk < 16; mk <<= 1) rs += __shfl_xor(rs, mk, 16);
      lrun[i] = lrun[i] * alpha + rs;
      #pragma unroll
      for (int j = 0; j < 4; ++j) { o[i][j] *= alpha; Pst[tx * 4 + j][ty * 4 + i] = p[j]; }
    }
    __syncthreads();

    // O += P V
    #pragma unroll 8
    for (int kk = 0; kk < 64; ++kk) {
      const float4 pa = *(const float4*)&Pst[kk][ty * 4];
      const float4 vb = *(const float4*)&Vs[kk][tx * 4];
      const float p[4] = {pa.x, pa.y, pa.z, pa.w};
      const float v[4] = {vb.x, vb.y, vb.z, vb.w};
      #pragma unroll
      for (int i = 0; i < 4; ++i)
        #pragma unroll
        for (int j = 0; j < 4; ++j) o[i][j] += p[i] * v[j];
    }
  }

  // normalize and write over the q region, (B,H,L,D)
  #pragma unroll
  for (int i = 0; i < 4; ++i) {
    const float inv = 1.f / lrun[i];
    *(float4*)(Qp + (size_t)(q0 + ty * 4 + i) * 64 + tx * 4) =
        make_float4(o[i][0]*inv, o[i][1]*inv, o[i][2]*inv, o[i][3]*inv);
  }
}

// ---------------------------------------------------------------------------
// Kernel 4: out = attn_out @ proj_w^T + b.  attn_out lives in the q region in
// (B,H,L,D) layout; gather A with k = h*64+d. Same 128x128x16 SGEMM.
// ---------------------------------------------------------------------------
__global__ __launch_bounds__(256) void proj_gemm_kernel(
    const float* __restrict__ ain, const float* __restrict__ w,
    const float* __restrict__ bias, float* __restrict__ out) {
  __shared__ float As[16][132];
  __shared__ float Bs[16][132];
  const int t  = threadIdx.x;
  const int tx = t & 15, ty = t >> 4;
  const int m0 = blockIdx.y * 128, n0 = blockIdx.x * 128;

  float acc[8][8];
  #pragma unroll
  for (int i = 0; i < 8; ++i)
    #pragma unroll
    for (int j = 0; j < 8; ++j) acc[i][j] = 0.f;

  for (int kt = 0; kt < CDIM; kt += 16) {
    #pragma unroll
    for (int s = 0; s < 2; ++s) {
      const int slot = t + s * 256;
      const int row = slot >> 2, c4 = (slot & 3) * 4;
      const int m = m0 + row;
      const int bb = m >> 11, l = m & 2047;
      const int k = kt + c4;
      const int hh = k >> 6, dd = k & 63;
      const float4 av = *(const float4*)(ain
          + (((size_t)((bb * HDIM + hh) * LDIM + l)) << 6) + dd);
      As[c4+0][row] = av.x; As[c4+1][row] = av.y; As[c4+2][row] = av.z; As[c4+3][row] = av.w;
      const float4 bv = *(const float4*)(w + (size_t)(n0 + row) * CDIM + kt + c4);
      Bs[c4+0][row] = bv.x; Bs[c4+1][row] = bv.y; Bs[c4+2][row] = bv.z; Bs[c4+3][row] = bv.w;
    }
    __syncthreads();
    #pragma unroll
    for (int kk = 0; kk < 16; ++kk) {
      float a[8], b[8];
      *(float4*)&a[0] = *(const float4*)&As[kk][ty * 8];
      *(float4*)&a[4] = *(const float4*)&As[kk][ty * 8 + 4];
      *(float4*)&b[0] = *(const float4*)&Bs[kk][tx * 8];
      *(float4*)&b[4] = *(const float4*)&Bs[kk][tx * 8 + 4];
      #pragma unroll
      for (int i = 0; i < 8; ++i)
        #pragma unroll
        for (int j = 0; j < 8; ++j) acc[i][j] += a[i] * b[j];
    }
    __syncthreads();
  }

  float bv[8];
  #pragma unroll
  for (int j = 0; j < 8; ++j) bv[j] = bias[n0 + tx * 8 + j];
  #pragma unroll
  for (int i = 0; i < 8; ++i) {
    const int m = m0 + ty * 8 + i;
    float* dst = out + (size_t)m * CDIM + n0 + tx * 8;
    *(float4*)(dst)     = make_float4(acc[i][0]+bv[0], acc[i][1]+bv[1],
                                      acc[i][2]+bv[2], acc[i][3]+bv[3]);
    *(float4*)(dst + 4) = make_float4(acc[i][4]+bv[4], acc[i][5]+bv[5],
                                      acc[i][6]+bv[6], acc[i][7]+bv[7]);
  }
}

// ---------------------------------------------------------------------------
extern "C" void kernel_launch(void* const* d_in, const int* in_sizes, int n_in,
                              void* d_out, int out_size, void* d_ws, size_t ws_size,
                              hipStream_t stream) {
  const float* x      = (const float*)d_in[0];
  const float* qkv_w  = (const float*)d_in[1];
  const float* qkv_b  = (const float*)d_in[2];
  const float* proj_w = (const float*)d_in[3];
  const float* proj_b = (const float*)d_in[4];
  const float* cosT   = (const float*)d_in[5];
  const float* sinT   = (const float*)d_in[6];
  float* out = (float*)d_out;
  float* qkv = (float*)d_ws;   // needs 3 * 4194304 * 4B = 50.3 MB of workspace

  // 1) QKV GEMM + scatter to (B,H,L,D)
  qkv_gemm_kernel<<<dim3(12, 64), 256, 0, stream>>>(x, qkv_w, qkv_b, qkv);
  // 2) RoPE in-place on q and k (131072 rows / 8 per block)
  rope_kernel<<<dim3(16384), 256, 0, stream>>>(qkv, cosT, sinT);
  // 3) flash attention, output overwrites q region
  attn_kernel<<<dim3(32, 32), 256, 0, stream>>>(qkv);
  // 4) output projection
  proj_gemm_kernel<<<dim3(4, 64), 256, 0, stream>>>(qkv, proj_w, proj_b, out);
}

// Round 2
// 349.390 us; speedup vs baseline: 2.6082x; 2.6082x over previous
//
#include <hip/hip_runtime.h>

// Problem constants (B=4, L=2048, C=512, H=8, D=64)
#define CDIM 512
#define LDIM 2048
#define BDIM 4
#define HDIM 8
#define DDIM 64

typedef __attribute__((ext_vector_type(8))) short bf16x8;
typedef __attribute__((ext_vector_type(4))) float f32x4;
typedef __attribute__((ext_vector_type(8))) unsigned short ushort8;

static __device__ __forceinline__ unsigned short f2bf(float f) {
  unsigned u = __float_as_uint(f);
  return (unsigned short)((u + 0x7FFFu + ((u >> 16) & 1u)) >> 16);
}
static __device__ __forceinline__ float bf2f(unsigned short h) {
  return __uint_as_float(((unsigned)h) << 16);
}

// ---------------------------------------------------------------------------
// Kernel 1: qkv = x @ qkv_w^T + b (fp32 compute). Epilogue applies RoPE to
// q/k in-register (partner via __shfl_xor(.,4)) and writes bf16:
//   q,k -> [b,h,l,d] row-major bf16 ; v -> [b,h][d][l] transposed bf16.
// typ = n>>9 is uniform per block (N-tile 128 never straddles a 512 boundary).
// ---------------------------------------------------------------------------
__global__ __launch_bounds__(256) void qkv_gemm_kernel(
    const float* __restrict__ x, const float* __restrict__ w,
    const float* __restrict__ bias, const float* __restrict__ cosT,
    const float* __restrict__ sinT, unsigned short* __restrict__ qb,
    unsigned short* __restrict__ kb, unsigned short* __restrict__ vt) {
  __shared__ float As[16][132];
  __shared__ float Bs[16][132];
  const int t  = threadIdx.x;
  const int tx = t & 15, ty = t >> 4;
  const int m0 = blockIdx.y * 128, n0 = blockIdx.x * 128;

  float acc[8][8];
  #pragma unroll
  for (int i = 0; i < 8; ++i)
    #pragma unroll
    for (int j = 0; j < 8; ++j) acc[i][j] = 0.f;

  for (int kt = 0; kt < CDIM; kt += 16) {
    #pragma unroll
    for (int s = 0; s < 2; ++s) {
      const int slot = t + s * 256;
      const int row = slot >> 2, c4 = (slot & 3) * 4;
      const float4 av = *(const float4*)(x + (size_t)(m0 + row) * CDIM + kt + c4);
      As[c4+0][row] = av.x; As[c4+1][row] = av.y; As[c4+2][row] = av.z; As[c4+3][row] = av.w;
      const float4 bv = *(const float4*)(w + (size_t)(n0 + row) * CDIM + kt + c4);
      Bs[c4+0][row] = bv.x; Bs[c4+1][row] = bv.y; Bs[c4+2][row] = bv.z; Bs[c4+3][row] = bv.w;
    }
    __syncthreads();
    #pragma unroll
    for (int kk = 0; kk < 16; ++kk) {
      float a[8], b[8];
      *(float4*)&a[0] = *(const float4*)&As[kk][ty * 8];
      *(float4*)&a[4] = *(const float4*)&As[kk][ty * 8 + 4];
      *(float4*)&b[0] = *(const float4*)&Bs[kk][tx * 8];
      *(float4*)&b[4] = *(const float4*)&Bs[kk][tx * 8 + 4];
      #pragma unroll
      for (int i = 0; i < 8; ++i)
        #pragma unroll
        for (int j = 0; j < 8; ++j) acc[i][j] += a[i] * b[j];
    }
    __syncthreads();
  }

  const int n   = n0 + tx * 8;
  const int typ = n >> 9;             // 0=q 1=k 2=v (uniform per block)
  const int hh  = (n >> 6) & 7;
  const int d0  = n & 63;
  const int bb  = m0 >> 11;           // whole block is one batch slice
  #pragma unroll
  for (int j = 0; j < 8; ++j) {
    const float bj = bias[n + j];
    #pragma unroll
    for (int i = 0; i < 8; ++i) acc[i][j] += bj;
  }

  if (typ == 2) {
    // V: transposed bf16 write. vt row = d, cols = 8 consecutive l.
    const int l0 = (m0 & 2047) + ty * 8;
    #pragma unroll
    for (int j = 0; j < 8; ++j) {
      ushort8 h;
      #pragma unroll
      for (int i = 0; i < 8; ++i) h[i] = f2bf(acc[i][j]);
      *(ushort8*)(vt + ((size_t)((bb * HDIM + hh) * DDIM + d0 + j)) * LDIM + l0) = h;
    }
  } else {
    unsigned short* dstb = typ ? kb : qb;
    const float sgn = (d0 < 32) ? -1.f : 1.f;   // rotate_half sign (8-col group uniform)
    #pragma unroll
    for (int i = 0; i < 8; ++i) {
      const int l = (m0 & 2047) + ty * 8 + i;
      float part[8];
      #pragma unroll
      for (int j = 0; j < 8; ++j) part[j] = __shfl_xor(acc[i][j], 4);  // x[d^32]
      const float4 c1 = *(const float4*)(cosT + l * 64 + d0);
      const float4 c2 = *(const float4*)(cosT + l * 64 + d0 + 4);
      const float4 s1 = *(const float4*)(sinT + l * 64 + d0);
      const float4 s2 = *(const float4*)(sinT + l * 64 + d0 + 4);
      const float cc[8] = {c1.x,c1.y,c1.z,c1.w,c2.x,c2.y,c2.z,c2.w};
      const float ss[8] = {s1.x,s1.y,s1.z,s1.w,s2.x,s2.y,s2.z,s2.w};
      ushort8 h;
      #pragma unroll
      for (int j = 0; j < 8; ++j) h[j] = f2bf(acc[i][j] * cc[j] + sgn * part[j] * ss[j]);
      *(ushort8*)(dstb + ((size_t)((bb * HDIM + hh) * LDIM + l)) * DDIM + d0) = h;
    }
  }
}

// ---------------------------------------------------------------------------
// Kernel 2: bf16 MFMA flash attention. Block = 4 waves x 16 q-rows = 64 q.
// KV tile 64. K tile [64 kv][64 d] and Vt tile [64 d][64 kv] staged bf16 via
// global_load_lds (16B) with pre-swizzled source (chunk ^= row&7) so fragment
// ds_read_b128 are bank-uniform. Q hoisted to registers. Online softmax is
// wave-parallel (shfl_xor over the 16-lane row group). P goes through a
// per-wave swizzled LDS tile to become the PV A-fragment. Output bf16 over qb.
// ---------------------------------------------------------------------------
__global__ __launch_bounds__(256) void attn_kernel(
    unsigned short* __restrict__ qb, const unsigned short* __restrict__ kb,
    const unsigned short* __restrict__ vt) {
  __shared__ char Ks[8192];
  __shared__ char Vs[8192];
  __shared__ char Pw[8192];
  const int t    = threadIdx.x;
  const int w    = t >> 6, lane = t & 63;
  const int lo   = lane & 15, hi = lane >> 4;
  const int bh   = blockIdx.y;
  const int q0   = blockIdx.x * 64 + w * 16;

  const char* Kb = (const char*)kb + (size_t)bh * (LDIM * DDIM * 2);
  const char* Vb = (const char*)vt + (size_t)bh * (LDIM * DDIM * 2);
  unsigned short* Qb = qb + (size_t)bh * (LDIM * DDIM);

  // hoist Q fragments (A-operand): lane holds Q[q0+lo][kd*32 + hi*8 .. +7]
  bf16x8 qf[2];
  #pragma unroll
  for (int kd = 0; kd < 2; ++kd)
    qf[kd] = *(const bf16x8*)((const char*)(Qb + (size_t)(q0 + lo) * DDIM)
                              + kd * 64 + hi * 16);

  f32x4 o[4];
  float mrun[4], lrun[4];
  #pragma unroll
  for (int r = 0; r < 4; ++r) {
    mrun[r] = -1e30f; lrun[r] = 0.f;
    o[r] = (f32x4){0.f, 0.f, 0.f, 0.f};
  }

  const int rloc = lane >> 3;                       // row within 8-row chunk
  const int sw   = ((lane & 7) ^ rloc) << 4;        // pre-swizzled chunk byte

  for (int kt = 0; kt < 32; ++kt) {
    // ---- stage K and Vt tiles (each wave: 2x1KB per tile) ----
    #pragma unroll
    for (int s = 0; s < 2; ++s) {
      const int r = (w * 2 + s) * 8 + rloc;
      __builtin_amdgcn_global_load_lds(
          (const __attribute__((address_space(1))) unsigned int*)
              (Kb + (size_t)(kt * 64 + r) * 128 + sw),
          (__attribute__((address_space(3))) unsigned int*)(Ks + (w * 2 + s) * 1024),
          16, 0, 0);
      __builtin_amdgcn_global_load_lds(
          (const __attribute__((address_space(1))) unsigned int*)
              (Vb + (size_t)r * (LDIM * 2) + kt * 128 + sw),
          (__attribute__((address_space(3))) unsigned int*)(Vs + (w * 2 + s) * 1024),
          16, 0, 0);
    }
    __syncthreads();

    // ---- S = scale * Q K^T : 4 key sub-tiles x 2 d-steps ----
    f32x4 sv[4];
    #pragma unroll
    for (int nt = 0; nt < 4; ++nt) {
      sv[nt] = (f32x4){0.f, 0.f, 0.f, 0.f};
      const int key = nt * 16 + lo;
      #pragma unroll
      for (int kd = 0; kd < 2; ++kd) {
        const bf16x8 kf = *(const bf16x8*)(Ks + key * 128
                            + (((kd * 4 + hi) ^ (key & 7)) << 4));
        sv[nt] = __builtin_amdgcn_mfma_f32_16x16x32_bf16(qf[kd], kf, sv[nt], 0, 0, 0);
      }
    }

    // ---- online softmax (per lane: 4 q-rows x 4 key-groups) ----
    char* Pwb = Pw + w * 2048;
    #pragma unroll
    for (int reg = 0; reg < 4; ++reg) {
      float v[4];
      #pragma unroll
      for (int nt = 0; nt < 4; ++nt) v[nt] = sv[nt][reg] * 0.125f;
      float mx = fmaxf(fmaxf(v[0], v[1]), fmaxf(v[2], v[3]));
      #pragma unroll
      for (int mk = 1; mk < 16; mk <<= 1) mx = fmaxf(mx, __shfl_xor(mx, mk));
      const float newm = fmaxf(mrun[reg], mx);
      const float al   = __expf(mrun[reg] - newm);
      mrun[reg] = newm;
      float p[4], rs = 0.f;
      #pragma unroll
      for (int nt = 0; nt < 4; ++nt) { p[nt] = __expf(v[nt] - newm); rs += p[nt]; }
      #pragma unroll
      for (int mk = 1; mk < 16; mk <<= 1) rs += __shfl_xor(rs, mk);
      lrun[reg] = lrun[reg] * al + rs;
      #pragma unroll
      for (int dt = 0; dt < 4; ++dt) o[dt][reg] *= al;
      const int q = hi * 4 + reg;
      #pragma unroll
      for (int nt = 0; nt < 4; ++nt) {
        const int key = nt * 16 + lo;
        *(unsigned short*)(Pwb + q * 128 + ((key * 2) ^ ((q & 7) << 4))) = f2bf(p[nt]);
      }
    }

    // ---- O += P V : A = P from LDS, B = Vt rows ----
    #pragma unroll
    for (int ks = 0; ks < 2; ++ks) {
      const bf16x8 pf = *(const bf16x8*)(Pwb + lo * 128
                          + (((ks * 4 + hi) ^ (lo & 7)) << 4));
      #pragma unroll
      for (int dt = 0; dt < 4; ++dt) {
        const int d = dt * 16 + lo;
        const bf16x8 vf = *(const bf16x8*)(Vs + d * 128
                            + (((ks * 4 + hi) ^ (d & 7)) << 4));
        o[dt] = __builtin_amdgcn_mfma_f32_16x16x32_bf16(pf, vf, o[dt], 0, 0, 0);
      }
    }
    __syncthreads();   // all waves done with K/Vt before next stage
  }

  // ---- normalize + write bf16 output over the q buffer ----
  #pragma unroll
  for (int reg = 0; reg < 4; ++reg) {
    const float inv = 1.f / lrun[reg];
    const int q = q0 + hi * 4 + reg;
    #pragma unroll
    for (int dt = 0; dt < 4; ++dt)
      Qb[(size_t)q * DDIM + dt * 16 + lo] = f2bf(o[dt][reg] * inv);
  }
}

// ---------------------------------------------------------------------------
// Kernel 3: out = attn_out @ proj_w^T + b. attn_out is bf16 in (B,H,L,D)
// (the qb region); gather A with k = h*64+d, convert on stage. fp32 compute.
// ---------------------------------------------------------------------------
__global__ __launch_bounds__(256) void proj_gemm_kernel(
    const unsigned short* __restrict__ ain, const float* __restrict__ w,
    const float* __restrict__ bias, float* __restrict__ out) {
  __shared__ float As[16][132];
  __shared__ float Bs[16][132];
  const int t  = threadIdx.x;
  const int tx = t & 15, ty = t >> 4;
  const int m0 = blockIdx.y * 128, n0 = blockIdx.x * 128;

  float acc[8][8];
  #pragma unroll
  for (int i = 0; i < 8; ++i)
    #pragma unroll
    for (int j = 0; j < 8; ++j) acc[i][j] = 0.f;

  for (int kt = 0; kt < CDIM; kt += 16) {
    #pragma unroll
    for (int s = 0; s < 2; ++s) {
      const int slot = t + s * 256;
      const int row = slot >> 2, c4 = (slot & 3) * 4;
      const int m = m0 + row;
      const int bb = m >> 11, l = m & 2047;
      const int k = kt + c4;
      const int hh2 = k >> 6, dd = k & 63;
      const ushort4 av = *(const ushort4*)(ain
          + (((size_t)((bb * HDIM + hh2) * LDIM + l)) << 6) + dd);
      As[c4+0][row] = bf2f(av.x); As[c4+1][row] = bf2f(av.y);
      As[c4+2][row] = bf2f(av.z); As[c4+3][row] = bf2f(av.w);
      const float4 bv = *(const float4*)(w + (size_t)(n0 + row) * CDIM + kt + c4);
      Bs[c4+0][row] = bv.x; Bs[c4+1][row] = bv.y; Bs[c4+2][row] = bv.z; Bs[c4+3][row] = bv.w;
    }
    __syncthreads();
    #pragma unroll
    for (int kk = 0; kk < 16; ++kk) {
      float a[8], b[8];
      *(float4*)&a[0] = *(const float4*)&As[kk][ty * 8];
      *(float4*)&a[4] = *(const float4*)&As[kk][ty * 8 + 4];
      *(float4*)&b[0] = *(const float4*)&Bs[kk][tx * 8];
      *(float4*)&b[4] = *(const float4*)&Bs[kk][tx * 8 + 4];
      #pragma unroll
      for (int i = 0; i < 8; ++i)
        #pragma unroll
        for (int j = 0; j < 8; ++j) acc[i][j] += a[i] * b[j];
    }
    __syncthreads();
  }

  float bv[8];
  #pragma unroll
  for (int j = 0; j < 8; ++j) bv[j] = bias[n0 + tx * 8 + j];
  #pragma unroll
  for (int i = 0; i < 8; ++i) {
    const int m = m0 + ty * 8 + i;
    float* dst = out + (size_t)m * CDIM + n0 + tx * 8;
    *(float4*)(dst)     = make_float4(acc[i][0]+bv[0], acc[i][1]+bv[1],
                                      acc[i][2]+bv[2], acc[i][3]+bv[3]);
    *(float4*)(dst + 4) = make_float4(acc[i][4]+bv[4], acc[i][5]+bv[5],
                                      acc[i][6]+bv[6], acc[i][7]+bv[7]);
  }
}

// ---------------------------------------------------------------------------
extern "C" void kernel_launch(void* const* d_in, const int* in_sizes, int n_in,
                              void* d_out, int out_size, void* d_ws, size_t ws_size,
                              hipStream_t stream) {
  const float* x      = (const float*)d_in[0];
  const float* qkv_w  = (const float*)d_in[1];
  const float* qkv_b  = (const float*)d_in[2];
  const float* proj_w = (const float*)d_in[3];
  const float* proj_b = (const float*)d_in[4];
  const float* cosT   = (const float*)d_in[5];
  const float* sinT   = (const float*)d_in[6];
  float* out = (float*)d_out;

  // ws layout (bf16): qb 8MB | kb 8MB | vt 8MB   (attn out overwrites qb)
  unsigned short* qb = (unsigned short*)d_ws;
  unsigned short* kb = qb + (size_t)BDIM * HDIM * LDIM * DDIM;
  unsigned short* vt = kb + (size_t)BDIM * HDIM * LDIM * DDIM;

  // 1) QKV GEMM + fused RoPE + bf16 scatter (q,k row-major; v transposed)
  qkv_gemm_kernel<<<dim3(12, 64), 256, 0, stream>>>(x, qkv_w, qkv_b, cosT, sinT,
                                                    qb, kb, vt);
  // 2) bf16 MFMA flash attention (output bf16 over qb)
  attn_kernel<<<dim3(32, 32), 256, 0, stream>>>(qb, kb, vt);
  // 3) output projection (bf16 A, fp32 compute)
  proj_gemm_kernel<<<dim3(4, 64), 256, 0, stream>>>(qb, proj_w, proj_b, out);
}

// Round 3
// 166.837 us; speedup vs baseline: 5.4622x; 2.0942x over previous
//
#include <hip/hip_runtime.h>

// Problem constants (B=4, L=2048, C=512, H=8, D=64)
#define CDIM 512
#define LDIM 2048
#define BDIM 4
#define HDIM 8
#define DDIM 64

typedef __attribute__((ext_vector_type(8))) short bf16x8;
typedef __attribute__((ext_vector_type(4))) float f32x4;
typedef __attribute__((ext_vector_type(8))) unsigned short ushort8;

static __device__ __forceinline__ unsigned short f2bf(float f) {
  unsigned u = __float_as_uint(f);
  return (unsigned short)((u + 0x7FFFu + ((u >> 16) & 1u)) >> 16);
}
static __device__ __forceinline__ float bf2f(unsigned short h) {
  return __uint_as_float(((unsigned)h) << 16);
}

// ---------------------------------------------------------------------------
// Kernel 0: fp32 -> bf16 convert of x (4194304), qkv_w (786432), proj_w
// (262144). 8 floats/thread, exact grid (5242880/8/256 = 2560 blocks).
// ---------------------------------------------------------------------------
__global__ __launch_bounds__(256) void convert_kernel(
    const float* __restrict__ x, const float* __restrict__ qw,
    const float* __restrict__ pw, unsigned short* __restrict__ xb,
    unsigned short* __restrict__ wb, unsigned short* __restrict__ pwb) {
  const size_t i = ((size_t)blockIdx.x * 256 + threadIdx.x) * 8;
  const float* src; unsigned short* dst; size_t off;
  if (i < 4194304) { src = x;  dst = xb;  off = i; }
  else if (i < 4980736) { src = qw; dst = wb;  off = i - 4194304; }
  else { src = pw; dst = pwb; off = i - 4980736; }
  const float4 a = *(const float4*)(src + off);
  const float4 b = *(const float4*)(src + off + 4);
  ushort8 h;
  h[0] = f2bf(a.x); h[1] = f2bf(a.y); h[2] = f2bf(a.z); h[3] = f2bf(a.w);
  h[4] = f2bf(b.x); h[5] = f2bf(b.y); h[6] = f2bf(b.z); h[7] = f2bf(b.w);
  *(ushort8*)(dst + off) = h;
}

// ---------------------------------------------------------------------------
// Kernel 1: qkv = x @ qkv_w^T + b via bf16 MFMA, fused RoPE epilogue.
// 128x128 tile, BK=64, 4 waves (2x2), each wave 64x64 = 4x4 16x16 frags.
// LDS rows 128B, chunk ^= row&7 swizzle, staged global_load_lds(16B) with
// pre-swizzled source. RoPE partner d^32 = same lane, fragment nt^2.
// Outputs bf16: q,k [b,h,l,d]; v transposed [b,h][d][l].
// ---------------------------------------------------------------------------
__global__ __launch_bounds__(256) void qkv_gemm_kernel(
    const unsigned short* __restrict__ xb, const unsigned short* __restrict__ wb,
    const float* __restrict__ bias, const float* __restrict__ cosT,
    const float* __restrict__ sinT, unsigned short* __restrict__ qb,
    unsigned short* __restrict__ kb, unsigned short* __restrict__ vt) {
  __shared__ char As[16384];
  __shared__ char Bs[16384];
  const int t  = threadIdx.x;
  const int w  = t >> 6, lane = t & 63;
  const int lo = lane & 15, hi = lane >> 4;
  const int wm = w >> 1, wn = w & 1;
  const int m0 = blockIdx.y * 128, n0 = blockIdx.x * 128;

  f32x4 acc[4][4];
  #pragma unroll
  for (int mt = 0; mt < 4; ++mt)
    #pragma unroll
    for (int nt = 0; nt < 4; ++nt) acc[mt][nt] = (f32x4){0.f, 0.f, 0.f, 0.f};

  const int srow   = t >> 3;                         // 0..31 row within slot
  const int schunk = ((t & 7) ^ (srow & 7)) << 4;    // pre-swizzled src byte
  const char* Ag = (const char*)xb;
  const char* Bg = (const char*)wb;

  for (int kt = 0; kt < CDIM; kt += 64) {
    #pragma unroll
    for (int s = 0; s < 4; ++s) {
      const int r = s * 32 + srow;
      __builtin_amdgcn_global_load_lds(
          (const __attribute__((address_space(1))) unsigned int*)
              (Ag + (size_t)(m0 + r) * 1024 + kt * 2 + schunk),
          (__attribute__((address_space(3))) unsigned int*)(As + s * 4096 + w * 1024),
          16, 0, 0);
      __builtin_amdgcn_global_load_lds(
          (const __attribute__((address_space(1))) unsigned int*)
              (Bg + (size_t)(n0 + r) * 1024 + kt * 2 + schunk),
          (__attribute__((address_space(3))) unsigned int*)(Bs + s * 4096 + w * 1024),
          16, 0, 0);
    }
    __syncthreads();
    #pragma unroll
    for (int ks = 0; ks < 2; ++ks) {
      bf16x8 af[4], bfr[4];
      #pragma unroll
      for (int mt = 0; mt < 4; ++mt)
        af[mt] = *(const bf16x8*)(As + (wm * 64 + mt * 16 + lo) * 128
                                  + (((ks * 4 + hi) ^ (lo & 7)) << 4));
      #pragma unroll
      for (int nt = 0; nt < 4; ++nt)
        bfr[nt] = *(const bf16x8*)(Bs + (wn * 64 + nt * 16 + lo) * 128
                                   + (((ks * 4 + hi) ^ (lo & 7)) << 4));
      #pragma unroll
      for (int mt = 0; mt < 4; ++mt)
        #pragma unroll
        for (int nt = 0; nt < 4; ++nt)
          acc[mt][nt] = __builtin_amdgcn_mfma_f32_16x16x32_bf16(
              af[mt], bfr[nt], acc[mt][nt], 0, 0, 0);
    }
    __syncthreads();
  }

  // ---- epilogue: bias, RoPE (q/k), bf16 scatter ----
  const int nbase = n0 + wn * 64;          // 64-aligned -> one (typ, head)
  const int typ   = nbase >> 9;            // 0=q 1=k 2=v
  const int hh    = (nbase >> 6) & 7;
  const int bb    = m0 >> 11;
  const int lbase = (m0 & 2047) + wm * 64;

  float bq[4];
  #pragma unroll
  for (int nt = 0; nt < 4; ++nt) bq[nt] = bias[nbase + nt * 16 + lo];
  #pragma unroll
  for (int mt = 0; mt < 4; ++mt)
    #pragma unroll
    for (int nt = 0; nt < 4; ++nt)
      #pragma unroll
      for (int reg = 0; reg < 4; ++reg) acc[mt][nt][reg] += bq[nt];

  if (typ == 2) {
    unsigned short* vbase = vt + (size_t)(bb * HDIM + hh) * DDIM * LDIM;
    #pragma unroll
    for (int mt = 0; mt < 4; ++mt)
      #pragma unroll
      for (int nt = 0; nt < 4; ++nt) {
        const int d = nt * 16 + lo;
        #pragma unroll
        for (int reg = 0; reg < 4; ++reg) {
          const int l = lbase + mt * 16 + hi * 4 + reg;
          vbase[(size_t)d * LDIM + l] = f2bf(acc[mt][nt][reg]);
        }
      }
  } else {
    unsigned short* dstb = (typ ? kb : qb) + (size_t)(bb * HDIM + hh) * LDIM * DDIM;
    #pragma unroll
    for (int mt = 0; mt < 4; ++mt)
      #pragma unroll
      for (int nt = 0; nt < 4; ++nt) {
        const int d   = nt * 16 + lo;
        const float sgn = (nt & 2) ? 1.f : -1.f;   // d>=32 ? +sin : -sin
        #pragma unroll
        for (int reg = 0; reg < 4; ++reg) {
          const int l = lbase + mt * 16 + hi * 4 + reg;
          const float c = cosT[l * 64 + d], s = sinT[l * 64 + d];
          const float v = acc[mt][nt][reg] * c + sgn * acc[mt][nt ^ 2][reg] * s;
          dstb[(size_t)l * DDIM + d] = f2bf(v);
        }
      }
  }
}

// ---------------------------------------------------------------------------
// Kernel 2: bf16 MFMA flash attention (unchanged from round 1).
// ---------------------------------------------------------------------------
__global__ __launch_bounds__(256) void attn_kernel(
    unsigned short* __restrict__ qb, const unsigned short* __restrict__ kb,
    const unsigned short* __restrict__ vt) {
  __shared__ char Ks[8192];
  __shared__ char Vs[8192];
  __shared__ char Pw[8192];
  const int t    = threadIdx.x;
  const int w    = t >> 6, lane = t & 63;
  const int lo   = lane & 15, hi = lane >> 4;
  const int bh   = blockIdx.y;
  const int q0   = blockIdx.x * 64 + w * 16;

  const char* Kb = (const char*)kb + (size_t)bh * (LDIM * DDIM * 2);
  const char* Vb = (const char*)vt + (size_t)bh * (LDIM * DDIM * 2);
  unsigned short* Qb = qb + (size_t)bh * (LDIM * DDIM);

  bf16x8 qf[2];
  #pragma unroll
  for (int kd = 0; kd < 2; ++kd)
    qf[kd] = *(const bf16x8*)((const char*)(Qb + (size_t)(q0 + lo) * DDIM)
                              + kd * 64 + hi * 16);

  f32x4 o[4];
  float mrun[4], lrun[4];
  #pragma unroll
  for (int r = 0; r < 4; ++r) {
    mrun[r] = -1e30f; lrun[r] = 0.f;
    o[r] = (f32x4){0.f, 0.f, 0.f, 0.f};
  }

  const int rloc = lane >> 3;
  const int sw   = ((lane & 7) ^ rloc) << 4;

  for (int kt = 0; kt < 32; ++kt) {
    #pragma unroll
    for (int s = 0; s < 2; ++s) {
      const int r = (w * 2 + s) * 8 + rloc;
      __builtin_amdgcn_global_load_lds(
          (const __attribute__((address_space(1))) unsigned int*)
              (Kb + (size_t)(kt * 64 + r) * 128 + sw),
          (__attribute__((address_space(3))) unsigned int*)(Ks + (w * 2 + s) * 1024),
          16, 0, 0);
      __builtin_amdgcn_global_load_lds(
          (const __attribute__((address_space(1))) unsigned int*)
              (Vb + (size_t)r * (LDIM * 2) + kt * 128 + sw),
          (__attribute__((address_space(3))) unsigned int*)(Vs + (w * 2 + s) * 1024),
          16, 0, 0);
    }
    __syncthreads();

    f32x4 sv[4];
    #pragma unroll
    for (int nt = 0; nt < 4; ++nt) {
      sv[nt] = (f32x4){0.f, 0.f, 0.f, 0.f};
      const int key = nt * 16 + lo;
      #pragma unroll
      for (int kd = 0; kd < 2; ++kd) {
        const bf16x8 kf = *(const bf16x8*)(Ks + key * 128
                            + (((kd * 4 + hi) ^ (key & 7)) << 4));
        sv[nt] = __builtin_amdgcn_mfma_f32_16x16x32_bf16(qf[kd], kf, sv[nt], 0, 0, 0);
      }
    }

    char* Pwb = Pw + w * 2048;
    #pragma unroll
    for (int reg = 0; reg < 4; ++reg) {
      float v[4];
      #pragma unroll
      for (int nt = 0; nt < 4; ++nt) v[nt] = sv[nt][reg] * 0.125f;
      float mx = fmaxf(fmaxf(v[0], v[1]), fmaxf(v[2], v[3]));
      #pragma unroll
      for (int mk = 1; mk < 16; mk <<= 1) mx = fmaxf(mx, __shfl_xor(mx, mk));
      const float newm = fmaxf(mrun[reg], mx);
      const float al   = __expf(mrun[reg] - newm);
      mrun[reg] = newm;
      float p[4], rs = 0.f;
      #pragma unroll
      for (int nt = 0; nt < 4; ++nt) { p[nt] = __expf(v[nt] - newm); rs += p[nt]; }
      #pragma unroll
      for (int mk = 1; mk < 16; mk <<= 1) rs += __shfl_xor(rs, mk);
      lrun[reg] = lrun[reg] * al + rs;
      #pragma unroll
      for (int dt = 0; dt < 4; ++dt) o[dt][reg] *= al;
      const int q = hi * 4 + reg;
      #pragma unroll
      for (int nt = 0; nt < 4; ++nt) {
        const int key = nt * 16 + lo;
        *(unsigned short*)(Pwb + q * 128 + ((key * 2) ^ ((q & 7) << 4))) = f2bf(p[nt]);
      }
    }

    #pragma unroll
    for (int ks = 0; ks < 2; ++ks) {
      const bf16x8 pf = *(const bf16x8*)(Pwb + lo * 128
                          + (((ks * 4 + hi) ^ (lo & 7)) << 4));
      #pragma unroll
      for (int dt = 0; dt < 4; ++dt) {
        const int d = dt * 16 + lo;
        const bf16x8 vf = *(const bf16x8*)(Vs + d * 128
                            + (((ks * 4 + hi) ^ (d & 7)) << 4));
        o[dt] = __builtin_amdgcn_mfma_f32_16x16x32_bf16(pf, vf, o[dt], 0, 0, 0);
      }
    }
    __syncthreads();
  }

  #pragma unroll
  for (int reg = 0; reg < 4; ++reg) {
    const float inv = 1.f / lrun[reg];
    const int q = q0 + hi * 4 + reg;
    #pragma unroll
    for (int dt = 0; dt < 4; ++dt)
      Qb[(size_t)q * DDIM + dt * 16 + lo] = f2bf(o[dt][reg] * inv);
  }
}

// ---------------------------------------------------------------------------
// Kernel 3: out = attn_out @ proj_w^T + b via bf16 MFMA. A = attn-out bf16 in
// (B,H,L,D) (qb region), k = h*64+d -> each k-tile of 64 is one head; rows
// are contiguous 128B. Same tile structure as kernel 1. fp32 output + bias.
// ---------------------------------------------------------------------------
__global__ __launch_bounds__(256) void proj_gemm_kernel(
    const unsigned short* __restrict__ ab, const unsigned short* __restrict__ pwb,
    const float* __restrict__ bias, float* __restrict__ out) {
  __shared__ char As[16384];
  __shared__ char Bs[16384];
  const int t  = threadIdx.x;
  const int w  = t >> 6, lane = t & 63;
  const int lo = lane & 15, hi = lane >> 4;
  const int wm = w >> 1, wn = w & 1;
  const int m0 = blockIdx.y * 128, n0 = blockIdx.x * 128;

  f32x4 acc[4][4];
  #pragma unroll
  for (int mt = 0; mt < 4; ++mt)
    #pragma unroll
    for (int nt = 0; nt < 4; ++nt) acc[mt][nt] = (f32x4){0.f, 0.f, 0.f, 0.f};

  const int srow   = t >> 3;
  const int schunk = ((t & 7) ^ (srow & 7)) << 4;
  const char* Ag = (const char*)ab;
  const char* Bg = (const char*)pwb;

  for (int kt = 0; kt < CDIM; kt += 64) {
    const int hh = kt >> 6;
    #pragma unroll
    for (int s = 0; s < 4; ++s) {
      const int r = s * 32 + srow;
      const int m = m0 + r;
      const int bb = m >> 11, l = m & 2047;
      __builtin_amdgcn_global_load_lds(
          (const __attribute__((address_space(1))) unsigned int*)
              (Ag + ((size_t)(bb * HDIM + hh) * LDIM + l) * 128 + schunk),
          (__attribute__((address_space(3))) unsigned int*)(As + s * 4096 + w * 1024),
          16, 0, 0);
      __builtin_amdgcn_global_load_lds(
          (const __attribute__((address_space(1))) unsigned int*)
              (Bg + (size_t)(n0 + r) * 1024 + kt * 2 + schunk),
          (__attribute__((address_space(3))) unsigned int*)(Bs + s * 4096 + w * 1024),
          16, 0, 0);
    }
    __syncthreads();
    #pragma unroll
    for (int ks = 0; ks < 2; ++ks) {
      bf16x8 af[4], bfr[4];
      #pragma unroll
      for (int mt = 0; mt < 4; ++mt)
        af[mt] = *(const bf16x8*)(As + (wm * 64 + mt * 16 + lo) * 128
                                  + (((ks * 4 + hi) ^ (lo & 7)) << 4));
      #pragma unroll
      for (int nt = 0; nt < 4; ++nt)
        bfr[nt] = *(const bf16x8*)(Bs + (wn * 64 + nt * 16 + lo) * 128
                                   + (((ks * 4 + hi) ^ (lo & 7)) << 4));
      #pragma unroll
      for (int mt = 0; mt < 4; ++mt)
        #pragma unroll
        for (int nt = 0; nt < 4; ++nt)
          acc[mt][nt] = __builtin_amdgcn_mfma_f32_16x16x32_bf16(
              af[mt], bfr[nt], acc[mt][nt], 0, 0, 0);
    }
    __syncthreads();
  }

  const int nn = n0 + wn * 64;
  float bp[4];
  #pragma unroll
  for (int nt = 0; nt < 4; ++nt) bp[nt] = bias[nn + nt * 16 + lo];
  #pragma unroll
  for (int mt = 0; mt < 4; ++mt)
    #pragma unroll
    for (int nt = 0; nt < 4; ++nt)
      #pragma unroll
      for (int reg = 0; reg < 4; ++reg) {
        const int m = m0 + wm * 64 + mt * 16 + hi * 4 + reg;
        out[(size_t)m * CDIM + nn + nt * 16 + lo] = acc[mt][nt][reg] + bp[nt];
      }
}

// ---------------------------------------------------------------------------
extern "C" void kernel_launch(void* const* d_in, const int* in_sizes, int n_in,
                              void* d_out, int out_size, void* d_ws, size_t ws_size,
                              hipStream_t stream) {
  const float* x      = (const float*)d_in[0];
  const float* qkv_w  = (const float*)d_in[1];
  const float* qkv_b  = (const float*)d_in[2];
  const float* proj_w = (const float*)d_in[3];
  const float* proj_b = (const float*)d_in[4];
  const float* cosT   = (const float*)d_in[5];
  const float* sinT   = (const float*)d_in[6];
  float* out = (float*)d_out;

  // ws layout (u16): qb 8MB | kb 8MB | vt 8MB | xb 8MB | wb 1.5MB | pwb 0.5MB
  unsigned short* qb  = (unsigned short*)d_ws;
  unsigned short* kb  = qb + (size_t)BDIM * HDIM * LDIM * DDIM;
  unsigned short* vt  = kb + (size_t)BDIM * HDIM * LDIM * DDIM;
  unsigned short* xb  = vt + (size_t)BDIM * HDIM * LDIM * DDIM;
  unsigned short* wb  = xb + (size_t)BDIM * LDIM * CDIM;
  unsigned short* pwb = wb + (size_t)3 * CDIM * CDIM;

  // 0) fp32 -> bf16 conversions
  convert_kernel<<<dim3(2560), 256, 0, stream>>>(x, qkv_w, proj_w, xb, wb, pwb);
  // 1) QKV GEMM (bf16 MFMA) + fused RoPE + scatter
  qkv_gemm_kernel<<<dim3(12, 64), 256, 0, stream>>>(xb, wb, qkv_b, cosT, sinT,
                                                    qb, kb, vt);
  // 2) bf16 MFMA flash attention (output bf16 over qb)
  attn_kernel<<<dim3(32, 32), 256, 0, stream>>>(qb, kb, vt);
  // 3) output projection (bf16 MFMA, fp32 out)
  proj_gemm_kernel<<<dim3(4, 64), 256, 0, stream>>>(qb, pwb, proj_b, out);
}

// Round 4
// 133.889 us; speedup vs baseline: 6.8063x; 1.2461x over previous
//
#include <hip/hip_runtime.h>

// Problem constants (B=4, L=2048, C=512, H=8, D=64)
#define CDIM 512
#define LDIM 2048
#define BDIM 4
#define HDIM 8
#define DDIM 64

typedef __attribute__((ext_vector_type(8))) short bf16x8;
typedef __attribute__((ext_vector_type(4))) float f32x4;
typedef __attribute__((ext_vector_type(8))) unsigned short ushort8;

static __device__ __forceinline__ unsigned short f2bf(float f) {
  unsigned u = __float_as_uint(f);
  return (unsigned short)((u + 0x7FFFu + ((u >> 16) & 1u)) >> 16);
}
static __device__ __forceinline__ float bf2f(unsigned short h) {
  return __uint_as_float(((unsigned)h) << 16);
}

// ---------------------------------------------------------------------------
// Kernel 0: fp32 -> bf16 convert of x (4194304), qkv_w (786432), proj_w
// (262144). 8 floats/thread, exact grid (5242880/8/256 = 2560 blocks).
// ---------------------------------------------------------------------------
__global__ __launch_bounds__(256) void convert_kernel(
    const float* __restrict__ x, const float* __restrict__ qw,
    const float* __restrict__ pw, unsigned short* __restrict__ xb,
    unsigned short* __restrict__ wb, unsigned short* __restrict__ pwb) {
  const size_t i = ((size_t)blockIdx.x * 256 + threadIdx.x) * 8;
  const float* src; unsigned short* dst; size_t off;
  if (i < 4194304) { src = x;  dst = xb;  off = i; }
  else if (i < 4980736) { src = qw; dst = wb;  off = i - 4194304; }
  else { src = pw; dst = pwb; off = i - 4980736; }
  const float4 a = *(const float4*)(src + off);
  const float4 b = *(const float4*)(src + off + 4);
  ushort8 h;
  h[0] = f2bf(a.x); h[1] = f2bf(a.y); h[2] = f2bf(a.z); h[3] = f2bf(a.w);
  h[4] = f2bf(b.x); h[5] = f2bf(b.y); h[6] = f2bf(b.z); h[7] = f2bf(b.w);
  *(ushort8*)(dst + off) = h;
}

// ---------------------------------------------------------------------------
// Kernel 1: qkv = x @ qkv_w^T + b via bf16 MFMA, fused RoPE epilogue.
// (unchanged from round 3)
// ---------------------------------------------------------------------------
__global__ __launch_bounds__(256) void qkv_gemm_kernel(
    const unsigned short* __restrict__ xb, const unsigned short* __restrict__ wb,
    const float* __restrict__ bias, const float* __restrict__ cosT,
    const float* __restrict__ sinT, unsigned short* __restrict__ qb,
    unsigned short* __restrict__ kb, unsigned short* __restrict__ vt) {
  __shared__ char As[16384];
  __shared__ char Bs[16384];
  const int t  = threadIdx.x;
  const int w  = t >> 6, lane = t & 63;
  const int lo = lane & 15, hi = lane >> 4;
  const int wm = w >> 1, wn = w & 1;
  const int m0 = blockIdx.y * 128, n0 = blockIdx.x * 128;

  f32x4 acc[4][4];
  #pragma unroll
  for (int mt = 0; mt < 4; ++mt)
    #pragma unroll
    for (int nt = 0; nt < 4; ++nt) acc[mt][nt] = (f32x4){0.f, 0.f, 0.f, 0.f};

  const int srow   = t >> 3;
  const int schunk = ((t & 7) ^ (srow & 7)) << 4;
  const char* Ag = (const char*)xb;
  const char* Bg = (const char*)wb;

  for (int kt = 0; kt < CDIM; kt += 64) {
    #pragma unroll
    for (int s = 0; s < 4; ++s) {
      const int r = s * 32 + srow;
      __builtin_amdgcn_global_load_lds(
          (const __attribute__((address_space(1))) unsigned int*)
              (Ag + (size_t)(m0 + r) * 1024 + kt * 2 + schunk),
          (__attribute__((address_space(3))) unsigned int*)(As + s * 4096 + w * 1024),
          16, 0, 0);
      __builtin_amdgcn_global_load_lds(
          (const __attribute__((address_space(1))) unsigned int*)
              (Bg + (size_t)(n0 + r) * 1024 + kt * 2 + schunk),
          (__attribute__((address_space(3))) unsigned int*)(Bs + s * 4096 + w * 1024),
          16, 0, 0);
    }
    __syncthreads();
    #pragma unroll
    for (int ks = 0; ks < 2; ++ks) {
      bf16x8 af[4], bfr[4];
      #pragma unroll
      for (int mt = 0; mt < 4; ++mt)
        af[mt] = *(const bf16x8*)(As + (wm * 64 + mt * 16 + lo) * 128
                                  + (((ks * 4 + hi) ^ (lo & 7)) << 4));
      #pragma unroll
      for (int nt = 0; nt < 4; ++nt)
        bfr[nt] = *(const bf16x8*)(Bs + (wn * 64 + nt * 16 + lo) * 128
                                   + (((ks * 4 + hi) ^ (lo & 7)) << 4));
      #pragma unroll
      for (int mt = 0; mt < 4; ++mt)
        #pragma unroll
        for (int nt = 0; nt < 4; ++nt)
          acc[mt][nt] = __builtin_amdgcn_mfma_f32_16x16x32_bf16(
              af[mt], bfr[nt], acc[mt][nt], 0, 0, 0);
    }
    __syncthreads();
  }

  const int nbase = n0 + wn * 64;
  const int typ   = nbase >> 9;
  const int hh    = (nbase >> 6) & 7;
  const int bb    = m0 >> 11;
  const int lbase = (m0 & 2047) + wm * 64;

  float bq[4];
  #pragma unroll
  for (int nt = 0; nt < 4; ++nt) bq[nt] = bias[nbase + nt * 16 + lo];
  #pragma unroll
  for (int mt = 0; mt < 4; ++mt)
    #pragma unroll
    for (int nt = 0; nt < 4; ++nt)
      #pragma unroll
      for (int reg = 0; reg < 4; ++reg) acc[mt][nt][reg] += bq[nt];

  if (typ == 2) {
    unsigned short* vbase = vt + (size_t)(bb * HDIM + hh) * DDIM * LDIM;
    #pragma unroll
    for (int mt = 0; mt < 4; ++mt)
      #pragma unroll
      for (int nt = 0; nt < 4; ++nt) {
        const int d = nt * 16 + lo;
        #pragma unroll
        for (int reg = 0; reg < 4; ++reg) {
          const int l = lbase + mt * 16 + hi * 4 + reg;
          vbase[(size_t)d * LDIM + l] = f2bf(acc[mt][nt][reg]);
        }
      }
  } else {
    unsigned short* dstb = (typ ? kb : qb) + (size_t)(bb * HDIM + hh) * LDIM * DDIM;
    #pragma unroll
    for (int mt = 0; mt < 4; ++mt)
      #pragma unroll
      for (int nt = 0; nt < 4; ++nt) {
        const int d   = nt * 16 + lo;
        const float sgn = (nt & 2) ? 1.f : -1.f;
        #pragma unroll
        for (int reg = 0; reg < 4; ++reg) {
          const int l = lbase + mt * 16 + hi * 4 + reg;
          const float c = cosT[l * 64 + d], s = sinT[l * 64 + d];
          const float v = acc[mt][nt][reg] * c + sgn * acc[mt][nt ^ 2][reg] * s;
          dstb[(size_t)l * DDIM + d] = f2bf(v);
        }
      }
  }
}

// ---------------------------------------------------------------------------
// Kernel 2: bf16 MFMA flash attention, swapped-QK^T in-register softmax.
// Block = 4 waves x 16 q-rows. KV tile 64.
//   S^T = mfma(A=K, B=Q): lane holds S[q=lo][key = nt*16 + hi*4 + reg] (16).
//   Softmax per-lane: max tree + 2 shfl; p = exp2(fma(s,c,-m*c)) (scale and
//   log2e folded into the FMA); truncate-to-bf16 by masking (sum of masked
//   values -> normalization cancels exactly); defer-max (THR=8 log2 units,
//   ballot-uniform) skips O-rescale on almost every iter.
//   P packed via v_perm -> 4x ds_write_b64 into swizzled [q][key] rows; PV
//   reads are unchanged from round 3.
// ---------------------------------------------------------------------------
#define CLOG2 0.18033688f          /* 0.125 * log2(e) */
#define RAW_THR 44.3614195f        /* 8 / CLOG2 */

__global__ __launch_bounds__(256) void attn_kernel(
    unsigned short* __restrict__ qb, const unsigned short* __restrict__ kb,
    const unsigned short* __restrict__ vt) {
  __shared__ char Ks[8192];
  __shared__ char Vs[8192];
  __shared__ char Pw[8192];
  const int t    = threadIdx.x;
  const int w    = t >> 6, lane = t & 63;
  const int lo   = lane & 15, hi = lane >> 4;
  const int bh   = blockIdx.y;
  const int q0   = blockIdx.x * 64 + w * 16;

  const char* Kb = (const char*)kb + (size_t)bh * (LDIM * DDIM * 2);
  const char* Vb = (const char*)vt + (size_t)bh * (LDIM * DDIM * 2);
  unsigned short* Qb = qb + (size_t)bh * (LDIM * DDIM);

  // Q fragments: lane holds Q[q0+lo][kd*32 + hi*8 .. +7] — valid as the
  // B-operand of mfma(K, Q) (same bits as the old A-operand).
  bf16x8 qf[2];
  #pragma unroll
  for (int kd = 0; kd < 2; ++kd)
    qf[kd] = *(const bf16x8*)((const char*)(Qb + (size_t)(q0 + lo) * DDIM)
                              + kd * 64 + hi * 16);

  f32x4 o[4];
  float mrun = -1e30f, lrun = 0.f;
  #pragma unroll
  for (int r = 0; r < 4; ++r) o[r] = (f32x4){0.f, 0.f, 0.f, 0.f};

  const int rloc = lane >> 3;
  const int sw   = ((lane & 7) ^ rloc) << 4;
  char* Pwb = Pw + w * 2048;

  for (int kt = 0; kt < 32; ++kt) {
    #pragma unroll
    for (int s = 0; s < 2; ++s) {
      const int r = (w * 2 + s) * 8 + rloc;
      __builtin_amdgcn_global_load_lds(
          (const __attribute__((address_space(1))) unsigned int*)
              (Kb + (size_t)(kt * 64 + r) * 128 + sw),
          (__attribute__((address_space(3))) unsigned int*)(Ks + (w * 2 + s) * 1024),
          16, 0, 0);
      __builtin_amdgcn_global_load_lds(
          (const __attribute__((address_space(1))) unsigned int*)
              (Vb + (size_t)r * (LDIM * 2) + kt * 128 + sw),
          (__attribute__((address_space(3))) unsigned int*)(Vs + (w * 2 + s) * 1024),
          16, 0, 0);
    }
    __syncthreads();

    // ---- S^T = K Q : lane gets 16 raw scores for q-row lo ----
    f32x4 sv[4];
    #pragma unroll
    for (int nt = 0; nt < 4; ++nt) {
      sv[nt] = (f32x4){0.f, 0.f, 0.f, 0.f};
      const int key = nt * 16 + lo;
      #pragma unroll
      for (int kd = 0; kd < 2; ++kd) {
        const bf16x8 kf = *(const bf16x8*)(Ks + key * 128
                            + (((kd * 4 + hi) ^ (key & 7)) << 4));
        sv[nt] = __builtin_amdgcn_mfma_f32_16x16x32_bf16(kf, qf[kd], sv[nt], 0, 0, 0);
      }
    }

    // ---- in-register online softmax (one q-row per lane) ----
    float mx = fmaxf(fmaxf(fmaxf(sv[0][0], sv[0][1]), fmaxf(sv[0][2], sv[0][3])),
                     fmaxf(fmaxf(sv[1][0], sv[1][1]), fmaxf(sv[1][2], sv[1][3])));
    mx = fmaxf(mx, fmaxf(fmaxf(fmaxf(sv[2][0], sv[2][1]), fmaxf(sv[2][2], sv[2][3])),
                         fmaxf(fmaxf(sv[3][0], sv[3][1]), fmaxf(sv[3][2], sv[3][3]))));
    mx = fmaxf(mx, __shfl_xor(mx, 16));
    mx = fmaxf(mx, __shfl_xor(mx, 32));

    if (__ballot(mx > mrun + RAW_THR)) {          // rescale (rare after iter 0)
      const float newm = fmaxf(mrun, mx);
      const float al   = exp2f((mrun - newm) * CLOG2);
      lrun *= al;
      mrun = newm;
      #pragma unroll
      for (int r = 0; r < 4; ++r) {
        const float aq = __shfl(al, (hi << 2) + r);
        #pragma unroll
        for (int dt = 0; dt < 4; ++dt) o[dt][r] *= aq;
      }
    }

    const float mc = mrun * CLOG2;
    float rs = 0.f;
    unsigned pb[16];
    #pragma unroll
    for (int nt = 0; nt < 4; ++nt)
      #pragma unroll
      for (int r = 0; r < 4; ++r) {
        const float pv = exp2f(fmaf(sv[nt][r], CLOG2, -mc));
        const unsigned tb = __float_as_uint(pv) & 0xffff0000u;  // trunc bf16
        rs += __uint_as_float(tb);
        pb[nt * 4 + r] = tb;
      }
    rs += __shfl_xor(rs, 16);
    rs += __shfl_xor(rs, 32);
    lrun += rs;

    // pack bf16 pairs, store P row q=lo as 4 x b64 (chunk16 ^ (q&7) swizzle)
    #pragma unroll
    for (int nt = 0; nt < 4; ++nt) {
      uint2 d2;
      d2.x = __builtin_amdgcn_perm(pb[nt*4+1], pb[nt*4+0], 0x07060302);
      d2.y = __builtin_amdgcn_perm(pb[nt*4+3], pb[nt*4+2], 0x07060302);
      *(uint2*)(Pwb + lo * 128 + ((nt * 32 + hi * 8) ^ ((lo & 7) << 4))) = d2;
    }

    // ---- O += P V (unchanged read pattern) ----
    #pragma unroll
    for (int ks = 0; ks < 2; ++ks) {
      const bf16x8 pf = *(const bf16x8*)(Pwb + lo * 128
                          + (((ks * 4 + hi) ^ (lo & 7)) << 4));
      #pragma unroll
      for (int dt = 0; dt < 4; ++dt) {
        const int d = dt * 16 + lo;
        const bf16x8 vf = *(const bf16x8*)(Vs + d * 128
                            + (((ks * 4 + hi) ^ (d & 7)) << 4));
        o[dt] = __builtin_amdgcn_mfma_f32_16x16x32_bf16(pf, vf, o[dt], 0, 0, 0);
      }
    }
    __syncthreads();
  }

  // ---- normalize (lrun broadcast per q-row) + bf16 output over qb ----
  #pragma unroll
  for (int r = 0; r < 4; ++r) {
    const float lr  = __shfl(lrun, (hi << 2) + r);
    const float inv = 1.f / lr;
    const int q = q0 + hi * 4 + r;
    #pragma unroll
    for (int dt = 0; dt < 4; ++dt)
      Qb[(size_t)q * DDIM + dt * 16 + lo] = f2bf(o[dt][r] * inv);
  }
}

// ---------------------------------------------------------------------------
// Kernel 3: out = attn_out @ proj_w^T + b via bf16 MFMA (unchanged).
// ---------------------------------------------------------------------------
__global__ __launch_bounds__(256) void proj_gemm_kernel(
    const unsigned short* __restrict__ ab, const unsigned short* __restrict__ pwb,
    const float* __restrict__ bias, float* __restrict__ out) {
  __shared__ char As[16384];
  __shared__ char Bs[16384];
  const int t  = threadIdx.x;
  const int w  = t >> 6, lane = t & 63;
  const int lo = lane & 15, hi = lane >> 4;
  const int wm = w >> 1, wn = w & 1;
  const int m0 = blockIdx.y * 128, n0 = blockIdx.x * 128;

  f32x4 acc[4][4];
  #pragma unroll
  for (int mt = 0; mt < 4; ++mt)
    #pragma unroll
    for (int nt = 0; nt < 4; ++nt) acc[mt][nt] = (f32x4){0.f, 0.f, 0.f, 0.f};

  const int srow   = t >> 3;
  const int schunk = ((t & 7) ^ (srow & 7)) << 4;
  const char* Ag = (const char*)ab;
  const char* Bg = (const char*)pwb;

  for (int kt = 0; kt < CDIM; kt += 64) {
    const int hh = kt >> 6;
    #pragma unroll
    for (int s = 0; s < 4; ++s) {
      const int r = s * 32 + srow;
      const int m = m0 + r;
      const int bb = m >> 11, l = m & 2047;
      __builtin_amdgcn_global_load_lds(
          (const __attribute__((address_space(1))) unsigned int*)
              (Ag + ((size_t)(bb * HDIM + hh) * LDIM + l) * 128 + schunk),
          (__attribute__((address_space(3))) unsigned int*)(As + s * 4096 + w * 1024),
          16, 0, 0);
      __builtin_amdgcn_global_load_lds(
          (const __attribute__((address_space(1))) unsigned int*)
              (Bg + (size_t)(n0 + r) * 1024 + kt * 2 + schunk),
          (__attribute__((address_space(3))) unsigned int*)(Bs + s * 4096 + w * 1024),
          16, 0, 0);
    }
    __syncthreads();
    #pragma unroll
    for (int ks = 0; ks < 2; ++ks) {
      bf16x8 af[4], bfr[4];
      #pragma unroll
      for (int mt = 0; mt < 4; ++mt)
        af[mt] = *(const bf16x8*)(As + (wm * 64 + mt * 16 + lo) * 128
                                  + (((ks * 4 + hi) ^ (lo & 7)) << 4));
      #pragma unroll
      for (int nt = 0; nt < 4; ++nt)
        bfr[nt] = *(const bf16x8*)(Bs + (wn * 64 + nt * 16 + lo) * 128
                                   + (((ks * 4 + hi) ^ (lo & 7)) << 4));
      #pragma unroll
      for (int mt = 0; mt < 4; ++mt)
        #pragma unroll
        for (int nt = 0; nt < 4; ++nt)
          acc[mt][nt] = __builtin_amdgcn_mfma_f32_16x16x32_bf16(
              af[mt], bfr[nt], acc[mt][nt], 0, 0, 0);
    }
    __syncthreads();
  }

  const int nn = n0 + wn * 64;
  float bp[4];
  #pragma unroll
  for (int nt = 0; nt < 4; ++nt) bp[nt] = bias[nn + nt * 16 + lo];
  #pragma unroll
  for (int mt = 0; mt < 4; ++mt)
    #pragma unroll
    for (int nt = 0; nt < 4; ++nt)
      #pragma unroll
      for (int reg = 0; reg < 4; ++reg) {
        const int m = m0 + wm * 64 + mt * 16 + hi * 4 + reg;
        out[(size_t)m * CDIM + nn + nt * 16 + lo] = acc[mt][nt][reg] + bp[nt];
      }
}

// ---------------------------------------------------------------------------
extern "C" void kernel_launch(void* const* d_in, const int* in_sizes, int n_in,
                              void* d_out, int out_size, void* d_ws, size_t ws_size,
                              hipStream_t stream) {
  const float* x      = (const float*)d_in[0];
  const float* qkv_w  = (const float*)d_in[1];
  const float* qkv_b  = (const float*)d_in[2];
  const float* proj_w = (const float*)d_in[3];
  const float* proj_b = (const float*)d_in[4];
  const float* cosT   = (const float*)d_in[5];
  const float* sinT   = (const float*)d_in[6];
  float* out = (float*)d_out;

  // ws layout (u16): qb 8MB | kb 8MB | vt 8MB | xb 8MB | wb 1.5MB | pwb 0.5MB
  unsigned short* qb  = (unsigned short*)d_ws;
  unsigned short* kb  = qb + (size_t)BDIM * HDIM * LDIM * DDIM;
  unsigned short* vt  = kb + (size_t)BDIM * HDIM * LDIM * DDIM;
  unsigned short* xb  = vt + (size_t)BDIM * HDIM * LDIM * DDIM;
  unsigned short* wb  = xb + (size_t)BDIM * LDIM * CDIM;
  unsigned short* pwb = wb + (size_t)3 * CDIM * CDIM;

  // 0) fp32 -> bf16 conversions
  convert_kernel<<<dim3(2560), 256, 0, stream>>>(x, qkv_w, proj_w, xb, wb, pwb);
  // 1) QKV GEMM (bf16 MFMA) + fused RoPE + scatter
  qkv_gemm_kernel<<<dim3(12, 64), 256, 0, stream>>>(xb, wb, qkv_b, cosT, sinT,
                                                    qb, kb, vt);
  // 2) bf16 MFMA flash attention (output bf16 over qb)
  attn_kernel<<<dim3(32, 32), 256, 0, stream>>>(qb, kb, vt);
  // 3) output projection (bf16 MFMA, fp32 out)
  proj_gemm_kernel<<<dim3(4, 64), 256, 0, stream>>>(qb, pwb, proj_b, out);
}

// Round 5
// 119.321 us; speedup vs baseline: 7.6373x; 1.1221x over previous
//
#include <hip/hip_runtime.h>

// Problem constants (B=4, L=2048, C=512, H=8, D=64)
#define CDIM 512
#define LDIM 2048
#define BDIM 4
#define HDIM 8
#define DDIM 64

typedef __attribute__((ext_vector_type(8))) short bf16x8;
typedef __attribute__((ext_vector_type(4))) float f32x4;
typedef __attribute__((ext_vector_type(8))) unsigned short ushort8;

static __device__ __forceinline__ unsigned short f2bf(float f) {
  unsigned u = __float_as_uint(f);
  return (unsigned short)((u + 0x7FFFu + ((u >> 16) & 1u)) >> 16);
}
static __device__ __forceinline__ float bf2f(unsigned short h) {
  return __uint_as_float(((unsigned)h) << 16);
}

// ---------------------------------------------------------------------------
// Kernel 0: fp32 -> bf16 convert of x (4194304), qkv_w (786432), proj_w
// (262144). 8 floats/thread, exact grid (5242880/8/256 = 2560 blocks).
// ---------------------------------------------------------------------------
__global__ __launch_bounds__(256) void convert_kernel(
    const float* __restrict__ x, const float* __restrict__ qw,
    const float* __restrict__ pw, unsigned short* __restrict__ xb,
    unsigned short* __restrict__ wb, unsigned short* __restrict__ pwb) {
  const size_t i = ((size_t)blockIdx.x * 256 + threadIdx.x) * 8;
  const float* src; unsigned short* dst; size_t off;
  if (i < 4194304) { src = x;  dst = xb;  off = i; }
  else if (i < 4980736) { src = qw; dst = wb;  off = i - 4194304; }
  else { src = pw; dst = pwb; off = i - 4980736; }
  const float4 a = *(const float4*)(src + off);
  const float4 b = *(const float4*)(src + off + 4);
  ushort8 h;
  h[0] = f2bf(a.x); h[1] = f2bf(a.y); h[2] = f2bf(a.z); h[3] = f2bf(a.w);
  h[4] = f2bf(b.x); h[5] = f2bf(b.y); h[6] = f2bf(b.z); h[7] = f2bf(b.w);
  *(ushort8*)(dst + off) = h;
}

// ---------------------------------------------------------------------------
// Kernel 1: qkv = x @ qkv_w^T + b via bf16 MFMA, fused RoPE epilogue.
// (unchanged)
// ---------------------------------------------------------------------------
__global__ __launch_bounds__(256) void qkv_gemm_kernel(
    const unsigned short* __restrict__ xb, const unsigned short* __restrict__ wb,
    const float* __restrict__ bias, const float* __restrict__ cosT,
    const float* __restrict__ sinT, unsigned short* __restrict__ qb,
    unsigned short* __restrict__ kb, unsigned short* __restrict__ vt) {
  __shared__ char As[16384];
  __shared__ char Bs[16384];
  const int t  = threadIdx.x;
  const int w  = t >> 6, lane = t & 63;
  const int lo = lane & 15, hi = lane >> 4;
  const int wm = w >> 1, wn = w & 1;
  const int m0 = blockIdx.y * 128, n0 = blockIdx.x * 128;

  f32x4 acc[4][4];
  #pragma unroll
  for (int mt = 0; mt < 4; ++mt)
    #pragma unroll
    for (int nt = 0; nt < 4; ++nt) acc[mt][nt] = (f32x4){0.f, 0.f, 0.f, 0.f};

  const int srow   = t >> 3;
  const int schunk = ((t & 7) ^ (srow & 7)) << 4;
  const char* Ag = (const char*)xb;
  const char* Bg = (const char*)wb;

  for (int kt = 0; kt < CDIM; kt += 64) {
    #pragma unroll
    for (int s = 0; s < 4; ++s) {
      const int r = s * 32 + srow;
      __builtin_amdgcn_global_load_lds(
          (const __attribute__((address_space(1))) unsigned int*)
              (Ag + (size_t)(m0 + r) * 1024 + kt * 2 + schunk),
          (__attribute__((address_space(3))) unsigned int*)(As + s * 4096 + w * 1024),
          16, 0, 0);
      __builtin_amdgcn_global_load_lds(
          (const __attribute__((address_space(1))) unsigned int*)
              (Bg + (size_t)(n0 + r) * 1024 + kt * 2 + schunk),
          (__attribute__((address_space(3))) unsigned int*)(Bs + s * 4096 + w * 1024),
          16, 0, 0);
    }
    __syncthreads();
    #pragma unroll
    for (int ks = 0; ks < 2; ++ks) {
      bf16x8 af[4], bfr[4];
      #pragma unroll
      for (int mt = 0; mt < 4; ++mt)
        af[mt] = *(const bf16x8*)(As + (wm * 64 + mt * 16 + lo) * 128
                                  + (((ks * 4 + hi) ^ (lo & 7)) << 4));
      #pragma unroll
      for (int nt = 0; nt < 4; ++nt)
        bfr[nt] = *(const bf16x8*)(Bs + (wn * 64 + nt * 16 + lo) * 128
                                   + (((ks * 4 + hi) ^ (lo & 7)) << 4));
      #pragma unroll
      for (int mt = 0; mt < 4; ++mt)
        #pragma unroll
        for (int nt = 0; nt < 4; ++nt)
          acc[mt][nt] = __builtin_amdgcn_mfma_f32_16x16x32_bf16(
              af[mt], bfr[nt], acc[mt][nt], 0, 0, 0);
    }
    __syncthreads();
  }

  const int nbase = n0 + wn * 64;
  const int typ   = nbase >> 9;
  const int hh    = (nbase >> 6) & 7;
  const int bb    = m0 >> 11;
  const int lbase = (m0 & 2047) + wm * 64;

  float bq[4];
  #pragma unroll
  for (int nt = 0; nt < 4; ++nt) bq[nt] = bias[nbase + nt * 16 + lo];
  #pragma unroll
  for (int mt = 0; mt < 4; ++mt)
    #pragma unroll
    for (int nt = 0; nt < 4; ++nt)
      #pragma unroll
      for (int reg = 0; reg < 4; ++reg) acc[mt][nt][reg] += bq[nt];

  if (typ == 2) {
    unsigned short* vbase = vt + (size_t)(bb * HDIM + hh) * DDIM * LDIM;
    #pragma unroll
    for (int mt = 0; mt < 4; ++mt)
      #pragma unroll
      for (int nt = 0; nt < 4; ++nt) {
        const int d = nt * 16 + lo;
        #pragma unroll
        for (int reg = 0; reg < 4; ++reg) {
          const int l = lbase + mt * 16 + hi * 4 + reg;
          vbase[(size_t)d * LDIM + l] = f2bf(acc[mt][nt][reg]);
        }
      }
  } else {
    unsigned short* dstb = (typ ? kb : qb) + (size_t)(bb * HDIM + hh) * LDIM * DDIM;
    #pragma unroll
    for (int mt = 0; mt < 4; ++mt)
      #pragma unroll
      for (int nt = 0; nt < 4; ++nt) {
        const int d   = nt * 16 + lo;
        const float sgn = (nt & 2) ? 1.f : -1.f;
        #pragma unroll
        for (int reg = 0; reg < 4; ++reg) {
          const int l = lbase + mt * 16 + hi * 4 + reg;
          const float c = cosT[l * 64 + d], s = sinT[l * 64 + d];
          const float v = acc[mt][nt][reg] * c + sgn * acc[mt][nt ^ 2][reg] * s;
          dstb[(size_t)l * DDIM + d] = f2bf(v);
        }
      }
  }
}

// ---------------------------------------------------------------------------
// Kernel 2: bf16 MFMA flash attention, no-max-pass softmax.
// Block = 8 waves x 16 q-rows = 128 q. KV tile 64; each wave stages 8 K-rows
// + 8 Vt-rows (1+1 global_load_lds).
//   S^T = mfma(K, Q): lane holds 16 raw scores for q-row lo.
//   Softmax fast path assumes mrun (=0) is a valid max bound: p = exp2(
//   fma(s,c,-mc)); per-iter partial sum ps; if __ballot(ps > 65536) -> rare
//   slow path (true max + rescale + recompute). Row-sum reduction deferred
//   to the end (no per-iter shfl). P packed via v_cvt_pk_bf16_f32 (RNE).
// ---------------------------------------------------------------------------
#define CLOG2 0.18033688f          /* 0.125 * log2(e) */

__global__ __launch_bounds__(512) void attn_kernel(
    unsigned short* __restrict__ qb, const unsigned short* __restrict__ kb,
    const unsigned short* __restrict__ vt) {
  __shared__ char Ks[8192];
  __shared__ char Vs[8192];
  __shared__ char Pw[16384];
  const int t    = threadIdx.x;
  const int w    = t >> 6, lane = t & 63;
  const int lo   = lane & 15, hi = lane >> 4;
  const int bh   = blockIdx.y;
  const int q0   = blockIdx.x * 128 + w * 16;

  const char* Kb = (const char*)kb + (size_t)bh * (LDIM * DDIM * 2);
  const char* Vb = (const char*)vt + (size_t)bh * (LDIM * DDIM * 2);
  unsigned short* Qb = qb + (size_t)bh * (LDIM * DDIM);

  // Q fragments (B-operand of mfma(K, Q)): lane holds Q[q0+lo][hi*8.. / +32]
  bf16x8 qf[2];
  #pragma unroll
  for (int kd = 0; kd < 2; ++kd)
    qf[kd] = *(const bf16x8*)((const char*)(Qb + (size_t)(q0 + lo) * DDIM)
                              + kd * 64 + hi * 16);

  f32x4 o[4];
  #pragma unroll
  for (int r = 0; r < 4; ++r) o[r] = (f32x4){0.f, 0.f, 0.f, 0.f};
  float mrun = 0.f;            // statistical bound; slow path fixes violations
  float mc   = 0.f;            // mrun * CLOG2
  float lpart = 0.f;           // per-lane partial row sum (reduced at end)

  const int rloc = lane >> 3;
  const int sw   = ((lane & 7) ^ rloc) << 4;
  char* Pwb = Pw + w * 2048;

  for (int kt = 0; kt < 32; ++kt) {
    // ---- stage: wave w loads K rows w*8..w*8+7 and Vt rows w*8..w*8+7 ----
    {
      const int r = w * 8 + rloc;
      __builtin_amdgcn_global_load_lds(
          (const __attribute__((address_space(1))) unsigned int*)
              (Kb + (size_t)(kt * 64 + r) * 128 + sw),
          (__attribute__((address_space(3))) unsigned int*)(Ks + w * 1024),
          16, 0, 0);
      __builtin_amdgcn_global_load_lds(
          (const __attribute__((address_space(1))) unsigned int*)
              (Vb + (size_t)r * (LDIM * 2) + kt * 128 + sw),
          (__attribute__((address_space(3))) unsigned int*)(Vs + w * 1024),
          16, 0, 0);
    }
    __syncthreads();

    // ---- S^T = K Q : lane gets 16 raw scores for q-row lo ----
    f32x4 sv[4];
    #pragma unroll
    for (int nt = 0; nt < 4; ++nt) {
      sv[nt] = (f32x4){0.f, 0.f, 0.f, 0.f};
      const int key = nt * 16 + lo;
      #pragma unroll
      for (int kd = 0; kd < 2; ++kd) {
        const bf16x8 kf = *(const bf16x8*)(Ks + key * 128
                            + (((kd * 4 + hi) ^ (key & 7)) << 4));
        sv[nt] = __builtin_amdgcn_mfma_f32_16x16x32_bf16(kf, qf[kd], sv[nt], 0, 0, 0);
      }
    }

    // ---- softmax fast path: no max pass ----
    float pv[16];
    float ps = 0.f;
    #pragma unroll
    for (int nt = 0; nt < 4; ++nt)
      #pragma unroll
      for (int r = 0; r < 4; ++r) {
        const float p = exp2f(fmaf(sv[nt][r], CLOG2, -mc));
        pv[nt * 4 + r] = p;
        ps += p;
      }

    if (__builtin_expect((bool)__ballot(ps > 65536.f), 0)) {
      // slow path: true row max, rescale history, recompute p
      float mx = -1e30f;
      #pragma unroll
      for (int i = 0; i < 16; ++i) mx = fmaxf(mx, ((const float*)sv)[i]);
      mx = fmaxf(mx, __shfl_xor(mx, 16));
      mx = fmaxf(mx, __shfl_xor(mx, 32));
      const float newm = fmaxf(mrun, mx);
      const float al   = exp2f((mrun - newm) * CLOG2);
      lpart *= al;
      #pragma unroll
      for (int r = 0; r < 4; ++r) {
        const float aq = __shfl(al, (hi << 2) + r);
        #pragma unroll
        for (int dt = 0; dt < 4; ++dt) o[dt][r] *= aq;
      }
      mrun = newm;
      mc   = mrun * CLOG2;
      ps = 0.f;
      #pragma unroll
      for (int i = 0; i < 16; ++i) {
        const float p = exp2f(fmaf(((const float*)sv)[i], CLOG2, -mc));
        pv[i] = p;
        ps += p;
      }
    }
    lpart += ps;

    // ---- pack P (RNE via v_cvt_pk_bf16_f32) and store 4x b64 ----
    #pragma unroll
    for (int nt = 0; nt < 4; ++nt) {
      unsigned w0, w1;
      asm("v_cvt_pk_bf16_f32 %0, %1, %2"
          : "=v"(w0) : "v"(pv[nt*4+0]), "v"(pv[nt*4+1]));
      asm("v_cvt_pk_bf16_f32 %0, %1, %2"
          : "=v"(w1) : "v"(pv[nt*4+2]), "v"(pv[nt*4+3]));
      uint2 d2; d2.x = w0; d2.y = w1;
      *(uint2*)(Pwb + lo * 128 + ((nt * 32 + hi * 8) ^ ((lo & 7) << 4))) = d2;
    }

    // ---- O += P V ----
    #pragma unroll
    for (int ks = 0; ks < 2; ++ks) {
      const bf16x8 pf = *(const bf16x8*)(Pwb + lo * 128
                          + (((ks * 4 + hi) ^ (lo & 7)) << 4));
      #pragma unroll
      for (int dt = 0; dt < 4; ++dt) {
        const int d = dt * 16 + lo;
        const bf16x8 vf = *(const bf16x8*)(Vs + d * 128
                            + (((ks * 4 + hi) ^ (d & 7)) << 4));
        o[dt] = __builtin_amdgcn_mfma_f32_16x16x32_bf16(pf, vf, o[dt], 0, 0, 0);
      }
    }
    __syncthreads();
  }

  // ---- final row-sum reduction + normalize + bf16 output over qb ----
  float rsum = lpart;
  rsum += __shfl_xor(rsum, 16);
  rsum += __shfl_xor(rsum, 32);
  #pragma unroll
  for (int r = 0; r < 4; ++r) {
    const float lr  = __shfl(rsum, (hi << 2) + r);
    const float inv = 1.f / lr;
    const int q = q0 + hi * 4 + r;
    #pragma unroll
    for (int dt = 0; dt < 4; ++dt)
      Qb[(size_t)q * DDIM + dt * 16 + lo] = f2bf(o[dt][r] * inv);
  }
}

// ---------------------------------------------------------------------------
// Kernel 3: out = attn_out @ proj_w^T + b via bf16 MFMA (unchanged).
// ---------------------------------------------------------------------------
__global__ __launch_bounds__(256) void proj_gemm_kernel(
    const unsigned short* __restrict__ ab, const unsigned short* __restrict__ pwb,
    const float* __restrict__ bias, float* __restrict__ out) {
  __shared__ char As[16384];
  __shared__ char Bs[16384];
  const int t  = threadIdx.x;
  const int w  = t >> 6, lane = t & 63;
  const int lo = lane & 15, hi = lane >> 4;
  const int wm = w >> 1, wn = w & 1;
  const int m0 = blockIdx.y * 128, n0 = blockIdx.x * 128;

  f32x4 acc[4][4];
  #pragma unroll
  for (int mt = 0; mt < 4; ++mt)
    #pragma unroll
    for (int nt = 0; nt < 4; ++nt) acc[mt][nt] = (f32x4){0.f, 0.f, 0.f, 0.f};

  const int srow   = t >> 3;
  const int schunk = ((t & 7) ^ (srow & 7)) << 4;
  const char* Ag = (const char*)ab;
  const char* Bg = (const char*)pwb;

  for (int kt = 0; kt < CDIM; kt += 64) {
    const int hh = kt >> 6;
    #pragma unroll
    for (int s = 0; s < 4; ++s) {
      const int r = s * 32 + srow;
      const int m = m0 + r;
      const int bb = m >> 11, l = m & 2047;
      __builtin_amdgcn_global_load_lds(
          (const __attribute__((address_space(1))) unsigned int*)
              (Ag + ((size_t)(bb * HDIM + hh) * LDIM + l) * 128 + schunk),
          (__attribute__((address_space(3))) unsigned int*)(As + s * 4096 + w * 1024),
          16, 0, 0);
      __builtin_amdgcn_global_load_lds(
          (const __attribute__((address_space(1))) unsigned int*)
              (Bg + (size_t)(n0 + r) * 1024 + kt * 2 + schunk),
          (__attribute__((address_space(3))) unsigned int*)(Bs + s * 4096 + w * 1024),
          16, 0, 0);
    }
    __syncthreads();
    #pragma unroll
    for (int ks = 0; ks < 2; ++ks) {
      bf16x8 af[4], bfr[4];
      #pragma unroll
      for (int mt = 0; mt < 4; ++mt)
        af[mt] = *(const bf16x8*)(As + (wm * 64 + mt * 16 + lo) * 128
                                  + (((ks * 4 + hi) ^ (lo & 7)) << 4));
      #pragma unroll
      for (int nt = 0; nt < 4; ++nt)
        bfr[nt] = *(const bf16x8*)(Bs + (wn * 64 + nt * 16 + lo) * 128
                                   + (((ks * 4 + hi) ^ (lo & 7)) << 4));
      #pragma unroll
      for (int mt = 0; mt < 4; ++mt)
        #pragma unroll
        for (int nt = 0; nt < 4; ++nt)
          acc[mt][nt] = __builtin_amdgcn_mfma_f32_16x16x32_bf16(
              af[mt], bfr[nt], acc[mt][nt], 0, 0, 0);
    }
    __syncthreads();
  }

  const int nn = n0 + wn * 64;
  float bp[4];
  #pragma unroll
  for (int nt = 0; nt < 4; ++nt) bp[nt] = bias[nn + nt * 16 + lo];
  #pragma unroll
  for (int mt = 0; mt < 4; ++mt)
    #pragma unroll
    for (int nt = 0; nt < 4; ++nt)
      #pragma unroll
      for (int reg = 0; reg < 4; ++reg) {
        const int m = m0 + wm * 64 + mt * 16 + hi * 4 + reg;
        out[(size_t)m * CDIM + nn + nt * 16 + lo] = acc[mt][nt][reg] + bp[nt];
      }
}

// ---------------------------------------------------------------------------
extern "C" void kernel_launch(void* const* d_in, const int* in_sizes, int n_in,
                              void* d_out, int out_size, void* d_ws, size_t ws_size,
                              hipStream_t stream) {
  const float* x      = (const float*)d_in[0];
  const float* qkv_w  = (const float*)d_in[1];
  const float* qkv_b  = (const float*)d_in[2];
  const float* proj_w = (const float*)d_in[3];
  const float* proj_b = (const float*)d_in[4];
  const float* cosT   = (const float*)d_in[5];
  const float* sinT   = (const float*)d_in[6];
  float* out = (float*)d_out;

  // ws layout (u16): qb 8MB | kb 8MB | vt 8MB | xb 8MB | wb 1.5MB | pwb 0.5MB
  unsigned short* qb  = (unsigned short*)d_ws;
  unsigned short* kb  = qb + (size_t)BDIM * HDIM * LDIM * DDIM;
  unsigned short* vt  = kb + (size_t)BDIM * HDIM * LDIM * DDIM;
  unsigned short* xb  = vt + (size_t)BDIM * HDIM * LDIM * DDIM;
  unsigned short* wb  = xb + (size_t)BDIM * LDIM * CDIM;
  unsigned short* pwb = wb + (size_t)3 * CDIM * CDIM;

  // 0) fp32 -> bf16 conversions
  convert_kernel<<<dim3(2560), 256, 0, stream>>>(x, qkv_w, proj_w, xb, wb, pwb);
  // 1) QKV GEMM (bf16 MFMA) + fused RoPE + scatter
  qkv_gemm_kernel<<<dim3(12, 64), 256, 0, stream>>>(xb, wb, qkv_b, cosT, sinT,
                                                    qb, kb, vt);
  // 2) bf16 MFMA flash attention (8 waves, output bf16 over qb)
  attn_kernel<<<dim3(16, 32), 512, 0, stream>>>(qb, kb, vt);
  // 3) output projection (bf16 MFMA, fp32 out)
  proj_gemm_kernel<<<dim3(4, 64), 256, 0, stream>>>(qb, pwb, proj_b, out);
}

// Round 6
// 110.098 us; speedup vs baseline: 8.2771x; 1.0838x over previous
//
#include <hip/hip_runtime.h>

// Problem constants (B=4, L=2048, C=512, H=8, D=64)
#define CDIM 512
#define LDIM 2048
#define BDIM 4
#define HDIM 8
#define DDIM 64

typedef __attribute__((ext_vector_type(8))) short bf16x8;
typedef __attribute__((ext_vector_type(4))) float f32x4;
typedef __attribute__((ext_vector_type(2))) float f32x2;
typedef __attribute__((ext_vector_type(8))) unsigned short ushort8;

static __device__ __forceinline__ unsigned short f2bf(float f) {
  unsigned u = __float_as_uint(f);
  return (unsigned short)((u + 0x7FFFu + ((u >> 16) & 1u)) >> 16);
}

// ---------------------------------------------------------------------------
// Kernel 0: fp32 -> bf16 convert of qkv_w (786432) + proj_w (262144) only
// (x conversion is now fused into qkv_gemm staging). 512 blocks x 256 thr.
// ---------------------------------------------------------------------------
__global__ __launch_bounds__(256) void convert_kernel(
    const float* __restrict__ qw, const float* __restrict__ pw,
    unsigned short* __restrict__ wb, unsigned short* __restrict__ pwb) {
  const size_t i = ((size_t)blockIdx.x * 256 + threadIdx.x) * 8;
  const float* src; unsigned short* dst; size_t off;
  if (i < 786432) { src = qw; dst = wb;  off = i; }
  else            { src = pw; dst = pwb; off = i - 786432; }
  const float4 a = *(const float4*)(src + off);
  const float4 b = *(const float4*)(src + off + 4);
  ushort8 h;
  h[0] = f2bf(a.x); h[1] = f2bf(a.y); h[2] = f2bf(a.z); h[3] = f2bf(a.w);
  h[4] = f2bf(b.x); h[5] = f2bf(b.y); h[6] = f2bf(b.z); h[7] = f2bf(b.w);
  *(ushort8*)(dst + off) = h;
}

// ---------------------------------------------------------------------------
// Kernel 1: qkv = x @ qkv_w^T + b via bf16 MFMA, fused RoPE epilogue.
// A-tile is reg-staged straight from fp32 x (dwordx4 x2 + v_cvt_pk_bf16_f32 x4
// + ds_write_b128 per thread) -- same LDS layout/swizzle as the old
// global_load_lds path, RNE-identical bits. B-tile stays global_load_lds.
// ---------------------------------------------------------------------------
__global__ __launch_bounds__(256) void qkv_gemm_kernel(
    const float* __restrict__ x, const unsigned short* __restrict__ wb,
    const float* __restrict__ bias, const float* __restrict__ cosT,
    const float* __restrict__ sinT, unsigned short* __restrict__ qb,
    unsigned short* __restrict__ kb, unsigned short* __restrict__ vt) {
  __shared__ char As[16384];
  __shared__ char Bs[16384];
  const int t  = threadIdx.x;
  const int w  = t >> 6, lane = t & 63;
  const int lo = lane & 15, hi = lane >> 4;
  const int wm = w >> 1, wn = w & 1;
  const int m0 = blockIdx.y * 128, n0 = blockIdx.x * 128;

  f32x4 acc[4][4];
  #pragma unroll
  for (int mt = 0; mt < 4; ++mt)
    #pragma unroll
    for (int nt = 0; nt < 4; ++nt) acc[mt][nt] = (f32x4){0.f, 0.f, 0.f, 0.f};

  const int srow   = t >> 3;                         // 0..31 row within slot
  const int sch    = (t & 7) ^ (srow & 7);           // swizzled chunk id
  const char* Bg = (const char*)wb;

  for (int kt = 0; kt < CDIM; kt += 64) {
    #pragma unroll
    for (int s = 0; s < 4; ++s) {
      const int r = s * 32 + srow;
      // A: fp32 load + convert + linear ds_write (source chunk pre-swizzled)
      const float4 f0 = *(const float4*)(x + (size_t)(m0 + r) * CDIM + kt + sch * 8);
      const float4 f1 = *(const float4*)(x + (size_t)(m0 + r) * CDIM + kt + sch * 8 + 4);
      unsigned u0, u1, u2, u3;
      asm("v_cvt_pk_bf16_f32 %0, %1, %2" : "=v"(u0) : "v"(f0.x), "v"(f0.y));
      asm("v_cvt_pk_bf16_f32 %0, %1, %2" : "=v"(u1) : "v"(f0.z), "v"(f0.w));
      asm("v_cvt_pk_bf16_f32 %0, %1, %2" : "=v"(u2) : "v"(f1.x), "v"(f1.y));
      asm("v_cvt_pk_bf16_f32 %0, %1, %2" : "=v"(u3) : "v"(f1.z), "v"(f1.w));
      uint4 uu; uu.x = u0; uu.y = u1; uu.z = u2; uu.w = u3;
      *(uint4*)(As + s * 4096 + t * 16) = uu;
      // B: async global->LDS
      __builtin_amdgcn_global_load_lds(
          (const __attribute__((address_space(1))) unsigned int*)
              (Bg + (size_t)(n0 + r) * 1024 + kt * 2 + sch * 16),
          (__attribute__((address_space(3))) unsigned int*)(Bs + s * 4096 + w * 1024),
          16, 0, 0);
    }
    __syncthreads();
    #pragma unroll
    for (int ks = 0; ks < 2; ++ks) {
      bf16x8 af[4], bfr[4];
      #pragma unroll
      for (int mt = 0; mt < 4; ++mt)
        af[mt] = *(const bf16x8*)(As + (wm * 64 + mt * 16 + lo) * 128
                                  + (((ks * 4 + hi) ^ (lo & 7)) << 4));
      #pragma unroll
      for (int nt = 0; nt < 4; ++nt)
        bfr[nt] = *(const bf16x8*)(Bs + (wn * 64 + nt * 16 + lo) * 128
                                   + (((ks * 4 + hi) ^ (lo & 7)) << 4));
      #pragma unroll
      for (int mt = 0; mt < 4; ++mt)
        #pragma unroll
        for (int nt = 0; nt < 4; ++nt)
          acc[mt][nt] = __builtin_amdgcn_mfma_f32_16x16x32_bf16(
              af[mt], bfr[nt], acc[mt][nt], 0, 0, 0);
    }
    __syncthreads();
  }

  const int nbase = n0 + wn * 64;
  const int typ   = nbase >> 9;
  const int hh    = (nbase >> 6) & 7;
  const int bb    = m0 >> 11;
  const int lbase = (m0 & 2047) + wm * 64;

  float bq[4];
  #pragma unroll
  for (int nt = 0; nt < 4; ++nt) bq[nt] = bias[nbase + nt * 16 + lo];
  #pragma unroll
  for (int mt = 0; mt < 4; ++mt)
    #pragma unroll
    for (int nt = 0; nt < 4; ++nt)
      #pragma unroll
      for (int reg = 0; reg < 4; ++reg) acc[mt][nt][reg] += bq[nt];

  if (typ == 2) {
    unsigned short* vbase = vt + (size_t)(bb * HDIM + hh) * DDIM * LDIM;
    #pragma unroll
    for (int mt = 0; mt < 4; ++mt)
      #pragma unroll
      for (int nt = 0; nt < 4; ++nt) {
        const int d = nt * 16 + lo;
        #pragma unroll
        for (int reg = 0; reg < 4; ++reg) {
          const int l = lbase + mt * 16 + hi * 4 + reg;
          vbase[(size_t)d * LDIM + l] = f2bf(acc[mt][nt][reg]);
        }
      }
  } else {
    unsigned short* dstb = (typ ? kb : qb) + (size_t)(bb * HDIM + hh) * LDIM * DDIM;
    #pragma unroll
    for (int mt = 0; mt < 4; ++mt)
      #pragma unroll
      for (int nt = 0; nt < 4; ++nt) {
        const int d   = nt * 16 + lo;
        const float sgn = (nt & 2) ? 1.f : -1.f;
        #pragma unroll
        for (int reg = 0; reg < 4; ++reg) {
          const int l = lbase + mt * 16 + hi * 4 + reg;
          const float c = cosT[l * 64 + d], s = sinT[l * 64 + d];
          const float v = acc[mt][nt][reg] * c + sgn * acc[mt][nt ^ 2][reg] * s;
          dstb[(size_t)l * DDIM + d] = f2bf(v);
        }
      }
  }
}

// ---------------------------------------------------------------------------
// Kernel 2: bf16 MFMA flash attention.
//  - double-buffered K/V LDS, counted s_waitcnt vmcnt(2) (stage latency hides
//    under a full iteration of compute; raw s_barrier, never vmcnt(0) drain)
//  - raw v_exp_f32 (inline asm; exp2f lowers to ~6 ops without fast-math)
//  - v_pk_fma_f32 for the packed scale-fma
//  - s_setprio(1) around MFMA clusters
// ---------------------------------------------------------------------------
#define CLOG2 0.18033688f          /* 0.125 * log2(e) */

__global__ __launch_bounds__(512) void attn_kernel(
    unsigned short* __restrict__ qb, const unsigned short* __restrict__ kb,
    const unsigned short* __restrict__ vt) {
  __shared__ char Ks[2][8192];
  __shared__ char Vs[2][8192];
  __shared__ char Pw[16384];
  const int t    = threadIdx.x;
  const int w    = t >> 6, lane = t & 63;
  const int lo   = lane & 15, hi = lane >> 4;
  const int bh   = blockIdx.y;
  const int q0   = blockIdx.x * 128 + w * 16;

  const char* Kb = (const char*)kb + (size_t)bh * (LDIM * DDIM * 2);
  const char* Vb = (const char*)vt + (size_t)bh * (LDIM * DDIM * 2);
  unsigned short* Qb = qb + (size_t)bh * (LDIM * DDIM);

  // Q fragments (B-operand of mfma(K, Q)): lane holds Q[q0+lo][hi*8.. / +32]
  bf16x8 qf[2];
  #pragma unroll
  for (int kd = 0; kd < 2; ++kd)
    qf[kd] = *(const bf16x8*)((const char*)(Qb + (size_t)(q0 + lo) * DDIM)
                              + kd * 64 + hi * 16);

  f32x4 o[4];
  #pragma unroll
  for (int r = 0; r < 4; ++r) o[r] = (f32x4){0.f, 0.f, 0.f, 0.f};
  float mrun = 0.f;            // statistical bound; slow path fixes violations
  float mc   = 0.f;            // mrun * CLOG2
  float lpart = 0.f;           // per-lane partial row sum (reduced at end)

  const int rloc = lane >> 3;
  const int sw   = ((lane & 7) ^ rloc) << 4;
  char* Pwb = Pw + w * 2048;

  auto stage = [&](int tile, int buf) {
    const int r = w * 8 + rloc;
    __builtin_amdgcn_global_load_lds(
        (const __attribute__((address_space(1))) unsigned int*)
            (Kb + (size_t)(tile * 64 + r) * 128 + sw),
        (__attribute__((address_space(3))) unsigned int*)(&Ks[buf][w * 1024]),
        16, 0, 0);
    __builtin_amdgcn_global_load_lds(
        (const __attribute__((address_space(1))) unsigned int*)
            (Vb + (size_t)r * (LDIM * 2) + tile * 128 + sw),
        (__attribute__((address_space(3))) unsigned int*)(&Vs[buf][w * 1024]),
        16, 0, 0);
  };

  stage(0, 0);   // prologue

  for (int kt = 0; kt < 32; ++kt) {
    const int cur = kt & 1;
    const int nk  = kt < 31 ? kt + 1 : 31;   // clamp: last prefetch is dummy
    stage(nk, cur ^ 1);
    asm volatile("s_waitcnt vmcnt(2)");      // current tile landed; next flies
    __builtin_amdgcn_s_barrier();
    __builtin_amdgcn_sched_barrier(0);

    // ---- S^T = K Q : lane gets 16 raw scores for q-row lo ----
    f32x4 sv[4];
    __builtin_amdgcn_s_setprio(1);
    #pragma unroll
    for (int nt = 0; nt < 4; ++nt) {
      sv[nt] = (f32x4){0.f, 0.f, 0.f, 0.f};
      const int key = nt * 16 + lo;
      #pragma unroll
      for (int kd = 0; kd < 2; ++kd) {
        const bf16x8 kf = *(const bf16x8*)(&Ks[cur][0] + key * 128
                            + (((kd * 4 + hi) ^ (key & 7)) << 4));
        sv[nt] = __builtin_amdgcn_mfma_f32_16x16x32_bf16(kf, qf[kd], sv[nt], 0, 0, 0);
      }
    }
    __builtin_amdgcn_s_setprio(0);

    // ---- softmax fast path: no max pass; pk_fma + raw v_exp_f32 ----
    const float* sflat = (const float*)sv;
    const f32x2 cc2 = {CLOG2, CLOG2};
    const f32x2 mm2 = {-mc, -mc};
    float pv[16];
    float ps = 0.f;
    #pragma unroll
    for (int i = 0; i < 8; ++i) {
      f32x2 a; a[0] = sflat[2*i]; a[1] = sflat[2*i+1];
      f32x2 xr;
      asm("v_pk_fma_f32 %0, %1, %2, %3" : "=v"(xr) : "v"(a), "v"(cc2), "v"(mm2));
      float p0, p1;
      asm("v_exp_f32 %0, %1" : "=v"(p0) : "v"(xr[0]));
      asm("v_exp_f32 %0, %1" : "=v"(p1) : "v"(xr[1]));
      pv[2*i] = p0; pv[2*i+1] = p1;
      ps += p0; ps += p1;
    }

    if (__builtin_expect((bool)__ballot(ps > 65536.f), 0)) {
      // slow path: true row max, rescale history, recompute p (cold, exact)
      float mx = -1e30f;
      #pragma unroll
      for (int i = 0; i < 16; ++i) mx = fmaxf(mx, sflat[i]);
      mx = fmaxf(mx, __shfl_xor(mx, 16));
      mx = fmaxf(mx, __shfl_xor(mx, 32));
      const float newm = fmaxf(mrun, mx);
      const float al   = exp2f((mrun - newm) * CLOG2);
      lpart *= al;
      #pragma unroll
      for (int r = 0; r < 4; ++r) {
        const float aq = __shfl(al, (hi << 2) + r);
        #pragma unroll
        for (int dt = 0; dt < 4; ++dt) o[dt][r] *= aq;
      }
      mrun = newm;
      mc   = mrun * CLOG2;
      ps = 0.f;
      #pragma unroll
      for (int i = 0; i < 16; ++i) {
        const float p = exp2f(fmaf(sflat[i], CLOG2, -mc));
        pv[i] = p;
        ps += p;
      }
    }
    lpart += ps;

    // ---- pack P (RNE via v_cvt_pk_bf16_f32) and store 4x b64 ----
    #pragma unroll
    for (int nt = 0; nt < 4; ++nt) {
      unsigned w0, w1;
      asm("v_cvt_pk_bf16_f32 %0, %1, %2"
          : "=v"(w0) : "v"(pv[nt*4+0]), "v"(pv[nt*4+1]));
      asm("v_cvt_pk_bf16_f32 %0, %1, %2"
          : "=v"(w1) : "v"(pv[nt*4+2]), "v"(pv[nt*4+3]));
      uint2 d2; d2.x = w0; d2.y = w1;
      *(uint2*)(Pwb + lo * 128 + ((nt * 32 + hi * 8) ^ ((lo & 7) << 4))) = d2;
    }

    // ---- O += P V ----
    __builtin_amdgcn_s_setprio(1);
    #pragma unroll
    for (int ks = 0; ks < 2; ++ks) {
      const bf16x8 pf = *(const bf16x8*)(Pwb + lo * 128
                          + (((ks * 4 + hi) ^ (lo & 7)) << 4));
      #pragma unroll
      for (int dt = 0; dt < 4; ++dt) {
        const int d = dt * 16 + lo;
        const bf16x8 vf = *(const bf16x8*)(&Vs[cur][0] + d * 128
                            + (((ks * 4 + hi) ^ (d & 7)) << 4));
        o[dt] = __builtin_amdgcn_mfma_f32_16x16x32_bf16(pf, vf, o[dt], 0, 0, 0);
      }
    }
    __builtin_amdgcn_s_setprio(0);

    __builtin_amdgcn_sched_barrier(0);
    __builtin_amdgcn_s_barrier();   // all reads of buf[cur] done before reuse
  }

  // ---- final row-sum reduction + normalize + bf16 output over qb ----
  float rsum = lpart;
  rsum += __shfl_xor(rsum, 16);
  rsum += __shfl_xor(rsum, 32);
  #pragma unroll
  for (int r = 0; r < 4; ++r) {
    const float lr  = __shfl(rsum, (hi << 2) + r);
    const float inv = 1.f / lr;
    const int q = q0 + hi * 4 + r;
    #pragma unroll
    for (int dt = 0; dt < 4; ++dt)
      Qb[(size_t)q * DDIM + dt * 16 + lo] = f2bf(o[dt][r] * inv);
  }
}

// ---------------------------------------------------------------------------
// Kernel 3: out = attn_out @ proj_w^T + b via bf16 MFMA (unchanged).
// ---------------------------------------------------------------------------
__global__ __launch_bounds__(256) void proj_gemm_kernel(
    const unsigned short* __restrict__ ab, const unsigned short* __restrict__ pwb,
    const float* __restrict__ bias, float* __restrict__ out) {
  __shared__ char As[16384];
  __shared__ char Bs[16384];
  const int t  = threadIdx.x;
  const int w  = t >> 6, lane = t & 63;
  const int lo = lane & 15, hi = lane >> 4;
  const int wm = w >> 1, wn = w & 1;
  const int m0 = blockIdx.y * 128, n0 = blockIdx.x * 128;

  f32x4 acc[4][4];
  #pragma unroll
  for (int mt = 0; mt < 4; ++mt)
    #pragma unroll
    for (int nt = 0; nt < 4; ++nt) acc[mt][nt] = (f32x4){0.f, 0.f, 0.f, 0.f};

  const int srow   = t >> 3;
  const int schunk = ((t & 7) ^ (srow & 7)) << 4;
  const char* Ag = (const char*)ab;
  const char* Bg = (const char*)pwb;

  for (int kt = 0; kt < CDIM; kt += 64) {
    const int hh = kt >> 6;
    #pragma unroll
    for (int s = 0; s < 4; ++s) {
      const int r = s * 32 + srow;
      const int m = m0 + r;
      const int bb = m >> 11, l = m & 2047;
      __builtin_amdgcn_global_load_lds(
          (const __attribute__((address_space(1))) unsigned int*)
              (Ag + ((size_t)(bb * HDIM + hh) * LDIM + l) * 128 + schunk),
          (__attribute__((address_space(3))) unsigned int*)(As + s * 4096 + w * 1024),
          16, 0, 0);
      __builtin_amdgcn_global_load_lds(
          (const __attribute__((address_space(1))) unsigned int*)
              (Bg + (size_t)(n0 + r) * 1024 + kt * 2 + schunk),
          (__attribute__((address_space(3))) unsigned int*)(Bs + s * 4096 + w * 1024),
          16, 0, 0);
    }
    __syncthreads();
    #pragma unroll
    for (int ks = 0; ks < 2; ++ks) {
      bf16x8 af[4], bfr[4];
      #pragma unroll
      for (int mt = 0; mt < 4; ++mt)
        af[mt] = *(const bf16x8*)(As + (wm * 64 + mt * 16 + lo) * 128
                                  + (((ks * 4 + hi) ^ (lo & 7)) << 4));
      #pragma unroll
      for (int nt = 0; nt < 4; ++nt)
        bfr[nt] = *(const bf16x8*)(Bs + (wn * 64 + nt * 16 + lo) * 128
                                   + (((ks * 4 + hi) ^ (lo & 7)) << 4));
      #pragma unroll
      for (int mt = 0; mt < 4; ++mt)
        #pragma unroll
        for (int nt = 0; nt < 4; ++nt)
          acc[mt][nt] = __builtin_amdgcn_mfma_f32_16x16x32_bf16(
              af[mt], bfr[nt], acc[mt][nt], 0, 0, 0);
    }
    __syncthreads();
  }

  const int nn = n0 + wn * 64;
  float bp[4];
  #pragma unroll
  for (int nt = 0; nt < 4; ++nt) bp[nt] = bias[nn + nt * 16 + lo];
  #pragma unroll
  for (int mt = 0; mt < 4; ++mt)
    #pragma unroll
    for (int nt = 0; nt < 4; ++nt)
      #pragma unroll
      for (int reg = 0; reg < 4; ++reg) {
        const int m = m0 + wm * 64 + mt * 16 + hi * 4 + reg;
        out[(size_t)m * CDIM + nn + nt * 16 + lo] = acc[mt][nt][reg] + bp[nt];
      }
}

// ---------------------------------------------------------------------------
extern "C" void kernel_launch(void* const* d_in, const int* in_sizes, int n_in,
                              void* d_out, int out_size, void* d_ws, size_t ws_size,
                              hipStream_t stream) {
  const float* x      = (const float*)d_in[0];
  const float* qkv_w  = (const float*)d_in[1];
  const float* qkv_b  = (const float*)d_in[2];
  const float* proj_w = (const float*)d_in[3];
  const float* proj_b = (const float*)d_in[4];
  const float* cosT   = (const float*)d_in[5];
  const float* sinT   = (const float*)d_in[6];
  float* out = (float*)d_out;

  // ws layout (u16): qb 8MB | kb 8MB | vt 8MB | wb 1.5MB | pwb 0.5MB
  unsigned short* qb  = (unsigned short*)d_ws;
  unsigned short* kb  = qb + (size_t)BDIM * HDIM * LDIM * DDIM;
  unsigned short* vt  = kb + (size_t)BDIM * HDIM * LDIM * DDIM;
  unsigned short* wb  = vt + (size_t)BDIM * HDIM * LDIM * DDIM;
  unsigned short* pwb = wb + (size_t)3 * CDIM * CDIM;

  // 0) fp32 -> bf16 weight conversions (x is converted inside qkv staging)
  convert_kernel<<<dim3(512), 256, 0, stream>>>(qkv_w, proj_w, wb, pwb);
  // 1) QKV GEMM (bf16 MFMA, fp32-x fused convert) + fused RoPE + scatter
  qkv_gemm_kernel<<<dim3(12, 64), 256, 0, stream>>>(x, wb, qkv_b, cosT, sinT,
                                                    qb, kb, vt);
  // 2) bf16 MFMA flash attention (8 waves, dbuf, counted vmcnt)
  attn_kernel<<<dim3(16, 32), 512, 0, stream>>>(qb, kb, vt);
  // 3) output projection (bf16 MFMA, fp32 out)
  proj_gemm_kernel<<<dim3(4, 64), 256, 0, stream>>>(qb, pwb, proj_b, out);
}